// Round 6
// baseline (6208.826 us; speedup 1.0000x reference)
//
#include <hip/hip_runtime.h>
#include <hip/hip_bf16.h>
#include <math.h>

#define Bn 8
#define Tn 898
#define Dn 1024
#define Hn 16
#define DHn 64
#define Ln 12
#define FFn 4096
#define Vn 1024
#define BT (Bn*Tn)   /* 7184 */

typedef short bf16x8 __attribute__((ext_vector_type(8)));
typedef float f32x4 __attribute__((ext_vector_type(4)));

__device__ __forceinline__ ushort f2bf(float f) {
    union { float f; unsigned u; } c; c.f = f;
    unsigned r = c.u + 0x7fffu + ((c.u >> 16) & 1u);
    return (ushort)(r >> 16);
}

__device__ __forceinline__ void glds16(const void* g, void* l) {
    __builtin_amdgcn_global_load_lds(
        (const __attribute__((address_space(1))) unsigned int*)g,
        (__attribute__((address_space(3))) unsigned int*)l, 16, 0, 0);
}

#define BARRIER() __builtin_amdgcn_s_barrier()
#define VMCNT4() asm volatile("s_waitcnt vmcnt(4)" ::: "memory")
#define VMCNT0() asm volatile("s_waitcnt vmcnt(0)" ::: "memory")

// ---------------- weight transpose + cast: f32 [K][N] -> bf16 [N][K] ----------------
__global__ __launch_bounds__(256) void transpose_cast_kernel(
    const float* __restrict__ in, ushort* __restrict__ out,
    int K, int N, size_t in_ls, size_t out_ls)
{
    __shared__ ushort t[64][68];
    const float* inp = in + (size_t)blockIdx.z * in_ls;
    ushort* outp = out + (size_t)blockIdx.z * out_ls;
    int n0 = blockIdx.x * 64, k0 = blockIdx.y * 64;
    int tx = threadIdx.x & 63, ty = threadIdx.x >> 6;
    #pragma unroll
    for (int p = 0; p < 16; p++) {
        int kl = p * 4 + ty;
        t[tx][kl] = f2bf(inp[(size_t)(k0 + kl) * N + n0 + tx]);
    }
    __syncthreads();
    int tx4 = threadIdx.x & 15, ty4 = threadIdx.x >> 4;
    #pragma unroll
    for (int p = 0; p < 4; p++) {
        int nl = p * 16 + ty4;
        ushort4 v;
        v.x = t[nl][4*tx4]; v.y = t[nl][4*tx4+1]; v.z = t[nl][4*tx4+2]; v.w = t[nl][4*tx4+3];
        *(ushort4*)&outp[(size_t)(n0 + nl) * K + k0 + 4*tx4] = v;
    }
}

// ---------------- embedding + positional encoding ----------------
__global__ __launch_bounds__(256) void embed_kernel(
    const int* __restrict__ tids, const int* __restrict__ pids, const int* __restrict__ oids,
    const float* __restrict__ ttab, const float* __restrict__ ptab, const float* __restrict__ otab,
    const float* __restrict__ sep, float* __restrict__ x)
{
    int bp = blockIdx.x;
    int b = bp / Tn, pos = bp - b * Tn;
    int d0 = threadIdx.x * 4;
    float4 r;
    if (pos == 128 || pos == 385) {
        r = *(const float4*)(sep + d0);
    } else {
        int t; int id; const float* tab;
        if (pos < 128)      { t = pos;       id = tids[b*128 + t]; tab = ttab; }
        else if (pos < 385) { t = pos - 129; id = pids[b*256 + t]; tab = ptab; }
        else                { t = pos - 386; id = oids[b*512 + t]; tab = otab; }
        float4 e = *(const float4*)(tab + (size_t)id * Dn + d0);
        float pe[4];
        #pragma unroll
        for (int i = 0; i < 4; i++) {
            int d = d0 + i;
            int ii = d & 511;
            float omega = expf(-9.210340371976184f * (float)ii * (1.0f/512.0f));
            float ang = (float)t * omega;
            pe[i] = (d < 512) ? sinf(ang) : cosf(ang);
        }
        r.x = e.x + pe[0]; r.y = e.y + pe[1]; r.z = e.z + pe[2]; r.w = e.w + pe[3];
    }
    *(float4*)(x + (size_t)bp * Dn + d0) = r;
}

// ---------------- layernorm fp32 -> bf16 ----------------
__global__ __launch_bounds__(256) void ln_kernel(
    const float* __restrict__ x, const float* __restrict__ g, const float* __restrict__ bt,
    ushort* __restrict__ out)
{
    __shared__ float red[8];
    int row = blockIdx.x, tid = threadIdx.x;
    float4 v = ((const float4*)(x + (size_t)row * Dn))[tid];
    float s = v.x + v.y + v.z + v.w;
    #pragma unroll
    for (int o = 32; o; o >>= 1) s += __shfl_down(s, o);
    if ((tid & 63) == 0) red[tid >> 6] = s;
    __syncthreads();
    float mu = (red[0] + red[1] + red[2] + red[3]) * (1.0f / Dn);
    float d0 = v.x - mu, d1 = v.y - mu, d2 = v.z - mu, d3 = v.w - mu;
    float s2 = d0*d0 + d1*d1 + d2*d2 + d3*d3;
    #pragma unroll
    for (int o = 32; o; o >>= 1) s2 += __shfl_down(s2, o);
    if ((tid & 63) == 0) red[4 + (tid >> 6)] = s2;
    __syncthreads();
    float var = (red[4] + red[5] + red[6] + red[7]) * (1.0f / Dn);
    float rstd = rsqrtf(var + 1e-5f);
    float4 gg = ((const float4*)g)[tid];
    float4 bb = ((const float4*)bt)[tid];
    ushort4 o4;
    o4.x = f2bf(d0 * rstd * gg.x + bb.x);
    o4.y = f2bf(d1 * rstd * gg.y + bb.y);
    o4.z = f2bf(d2 * rstd * gg.z + bb.z);
    o4.w = f2bf(d3 * rstd * gg.w + bb.w);
    ((ushort4*)(out + (size_t)row * Dn))[tid] = o4;
}

// ---------------- occupancy-pipelined GEMM: C = A(bf16 [M][K]) @ Bw(bf16 [N][K])^T --------
// 128x128 tile, 4 waves, BK=32, TRIPLE-buffered LDS (48KB -> 3 blocks/CU),
// stage issued 2 K-tiles ahead, counted vmcnt(4) (vmcnt(0) at tail), 1 barrier/K-tile,
// XOR-swizzled staging source + fragment reads (conflict-free), XCD-bijective grid swizzle.
// MODE 0: store bf16; MODE 1: f32 = resid + AB + bias; MODE 2: bf16 = gelu(AB + bias)
template<int MODE>
__global__ __launch_bounds__(256, 3) void gemm3_kernel(
    const ushort* __restrict__ A, const ushort* __restrict__ Bw,
    const float* __restrict__ bias, const float* __restrict__ resid,
    void* __restrict__ Cout, int M, int N, int K, int nx)
{
    __shared__ ushort sA[3][128 * 32];
    __shared__ ushort sB[3][128 * 32];

    int tid = threadIdx.x, lane = tid & 63, wv = tid >> 6;
    int wm = wv >> 1, wn = wv & 1;
    int l16 = lane & 15, lhi = lane >> 4;

    // bijective XCD-chunked swizzle
    int nb = gridDim.x, bid = blockIdx.x;
    int qq = nb >> 3, rr8 = nb & 7;
    int xcd = bid & 7, idx = bid >> 3;
    int wg = (xcd < rr8 ? xcd * (qq + 1) : rr8 * (qq + 1) + (xcd - rr8) * qq) + idx;
    int mt = wg / nx, ntt = wg - mt * nx;
    int m0 = mt * 128, n0 = ntt * 128;

    f32x4 acc[4][4];
    #pragma unroll
    for (int i = 0; i < 4; i++)
        #pragma unroll
        for (int j = 0; j < 4; j++) acc[i][j] = (f32x4){0.f, 0.f, 0.f, 0.f};

    // staging: each glds16 covers 16 rows x 64B; lane -> row (lane>>2), chunk (lane&3)^(row&3)
    const size_t K2 = (size_t)K * 2;
    int srow = lane >> 2;
    int schk = ((lane & 3) ^ (srow & 3)) * 16;
    const char* Ab = (const char*)A + (size_t)(m0 + srow) * K2 + schk;
    const char* Bb = (const char*)Bw + (size_t)(n0 + srow) * K2 + schk;
    const int r0 = wv * 32, r1 = wv * 32 + 16;

    auto stage = [&](int buf, int t) {
        size_t ko = (size_t)t * 64;
        glds16(Ab + (size_t)r0 * K2 + ko, (char*)&sA[buf][0] + r0 * 64);
        glds16(Ab + (size_t)r1 * K2 + ko, (char*)&sA[buf][0] + r1 * 64);
        glds16(Bb + (size_t)r0 * K2 + ko, (char*)&sB[buf][0] + r0 * 64);
        glds16(Bb + (size_t)r1 * K2 + ko, (char*)&sB[buf][0] + r1 * 64);
    };

    // fragment read swizzle: chunk = lhi ^ (row&3); row&3 == l16&3 for all frag rows
    const int sc = (lhi ^ (l16 & 3)) * 8;
    auto compute = [&](int buf) {
        bf16x8 af[4], bf[4];
        #pragma unroll
        for (int mi = 0; mi < 4; mi++)
            af[mi] = *(const bf16x8*)&sA[buf][(wm * 64 + mi * 16 + l16) * 32 + sc];
        #pragma unroll
        for (int ni = 0; ni < 4; ni++)
            bf[ni] = *(const bf16x8*)&sB[buf][(wn * 64 + ni * 16 + l16) * 32 + sc];
        #pragma unroll
        for (int mi = 0; mi < 4; mi++)
            #pragma unroll
            for (int ni = 0; ni < 4; ni++)
                acc[mi][ni] = __builtin_amdgcn_mfma_f32_16x16x32_bf16(af[mi], bf[ni], acc[mi][ni], 0, 0, 0);
    };

    int ntile = K >> 5;
    // prologue: stage tiles 0 and 1; wait for tile 0 (4 newest outstanding = tile 1)
    stage(0, 0);
    stage(1, 1);
    VMCNT4();
    BARRIER();

    int b = 0;
    for (int t = 0; t < ntile; ++t) {
        if (t + 2 < ntile) {
            int pbuf = b + 2; if (pbuf >= 3) pbuf -= 3;
            stage(pbuf, t + 2);          // issue early; lands before tile t+2
            compute(b);
            VMCNT4();                    // oldest (tile t+1) landed; t+2 in flight
        } else {
            compute(b);
            VMCNT0();                    // tail: no refill behind -> drain (R4 race fix)
        }
        BARRIER();
        if (++b == 3) b = 0;
    }

    // epilogue
    #pragma unroll
    for (int mi = 0; mi < 4; mi++) {
        int rl = wm * 64 + mi * 16 + lhi * 4;
        #pragma unroll
        for (int ni = 0; ni < 4; ni++) {
            int gcol = n0 + wn * 64 + ni * 16 + l16;
            float bs = (MODE == 0) ? 0.0f : bias[gcol];
            #pragma unroll
            for (int j = 0; j < 4; j++) {
                int grow = m0 + rl + j;
                if (grow >= M) continue;
                float v = acc[mi][ni][j] + bs;
                if (MODE == 1) {
                    float rv = resid[(size_t)grow * N + gcol];
                    ((float*)Cout)[(size_t)grow * N + gcol] = rv + v;
                } else if (MODE == 2) {
                    v = 0.5f * v * (1.0f + erff(v * 0.70710678118654752f));
                    ((ushort*)Cout)[(size_t)grow * N + gcol] = f2bf(v);
                } else {
                    ((ushort*)Cout)[(size_t)grow * N + gcol] = f2bf(v);
                }
            }
        }
    }
}

// ---------------- flash attention (causal), bf16 in/out ----------------
__global__ __launch_bounds__(256) void attn_kernel(
    const ushort* __restrict__ qkv, ushort* __restrict__ out)
{
    __shared__ ushort Ksm[64 * 72];
    __shared__ ushort Vsm[64 * 72];
    __shared__ ushort Psm[4][16 * 72];
    int qt = blockIdx.x, b = blockIdx.y, h = blockIdx.z;
    int tid = threadIdx.x, lane = tid & 63, wave = tid >> 6;
    int l16 = lane & 15, lhi = lane >> 4;

    int qrow = qt*64 + wave*16 + l16;
    bf16x8 qf0 = {}, qf1 = {};
    if (qrow < Tn) {
        const ushort* qp = qkv + (size_t)(b*Tn + qrow) * 3072 + h*64 + lhi*8;
        qf0 = *(const bf16x8*)qp;
        qf1 = *(const bf16x8*)(qp + 32);
    }

    f32x4 o[4];
    #pragma unroll
    for (int i = 0; i < 4; i++) o[i] = (f32x4){0.f,0.f,0.f,0.f};
    float mrun[4] = {-1e30f,-1e30f,-1e30f,-1e30f};
    float sume[4] = {0.f,0.f,0.f,0.f};

    int kr = tid >> 2, cc = (tid & 3) * 16;
    const ushort* kvbase = qkv + (size_t)(b*Tn) * 3072 + h*64 + cc;
    int qg = qt*64 + wave*16 + lhi*4;

    for (int jt = 0; jt <= qt; jt++) {
        int kvr = jt*64 + kr;
        uint4 k0 = make_uint4(0,0,0,0), k1 = k0, v0 = k0, v1 = k0;
        if (kvr < Tn) {
            const ushort* p = kvbase + (size_t)kvr * 3072;
            k0 = *(const uint4*)(p + 1024);
            k1 = *(const uint4*)(p + 1024 + 8);
            v0 = *(const uint4*)(p + 2048);
            v1 = *(const uint4*)(p + 2048 + 8);
        }
        __syncthreads();
        *(uint4*)&Ksm[kr * 72 + cc] = k0;
        *(uint4*)&Ksm[kr * 72 + cc + 8] = k1;
        {
            ushort vv[16];
            *(uint4*)&vv[0] = v0; *(uint4*)&vv[8] = v1;
            #pragma unroll
            for (int i = 0; i < 16; i++) Vsm[(cc + i) * 72 + kr] = vv[i];
        }
        __syncthreads();

        f32x4 s[4];
        #pragma unroll
        for (int ni = 0; ni < 4; ni++) {
            s[ni] = (f32x4){0.f,0.f,0.f,0.f};
            bf16x8 kf0 = *(const bf16x8*)&Ksm[(ni*16 + l16) * 72 + lhi*8];
            bf16x8 kf1 = *(const bf16x8*)&Ksm[(ni*16 + l16) * 72 + lhi*8 + 32];
            s[ni] = __builtin_amdgcn_mfma_f32_16x16x32_bf16(qf0, kf0, s[ni], 0, 0, 0);
            s[ni] = __builtin_amdgcn_mfma_f32_16x16x32_bf16(qf1, kf1, s[ni], 0, 0, 0);
        }

        float pv[4][4];
        #pragma unroll
        for (int j = 0; j < 4; j++) {
            int qgj = qg + j;
            float mx = -1e30f;
            #pragma unroll
            for (int ni = 0; ni < 4; ni++) {
                int kvg = jt*64 + ni*16 + l16;
                float e = (kvg <= qgj && kvg < Tn) ? s[ni][j] * 0.125f : -1e30f;
                pv[ni][j] = e;
                mx = fmaxf(mx, e);
            }
            #pragma unroll
            for (int m = 1; m < 16; m <<= 1) mx = fmaxf(mx, __shfl_xor(mx, m));
            float mnew = fmaxf(mrun[j], mx);
            float fac = expf(mrun[j] - mnew);
            mrun[j] = mnew;
            float rs = 0.f;
            #pragma unroll
            for (int ni = 0; ni < 4; ni++) { pv[ni][j] = expf(pv[ni][j] - mnew); rs += pv[ni][j]; }
            #pragma unroll
            for (int m = 1; m < 16; m <<= 1) rs += __shfl_xor(rs, m);
            sume[j] = sume[j] * fac + rs;
            #pragma unroll
            for (int di = 0; di < 4; di++) o[di][j] *= fac;
        }

        #pragma unroll
        for (int j = 0; j < 4; j++)
            #pragma unroll
            for (int ni = 0; ni < 4; ni++)
                Psm[wave][(lhi*4 + j) * 72 + ni*16 + l16] = f2bf(pv[ni][j]);
        __syncthreads();

        bf16x8 pf0 = *(const bf16x8*)&Psm[wave][l16 * 72 + lhi*8];
        bf16x8 pf1 = *(const bf16x8*)&Psm[wave][l16 * 72 + lhi*8 + 32];
        #pragma unroll
        for (int di = 0; di < 4; di++) {
            bf16x8 vf0 = *(const bf16x8*)&Vsm[(di*16 + l16) * 72 + lhi*8];
            bf16x8 vf1 = *(const bf16x8*)&Vsm[(di*16 + l16) * 72 + lhi*8 + 32];
            o[di] = __builtin_amdgcn_mfma_f32_16x16x32_bf16(pf0, vf0, o[di], 0, 0, 0);
            o[di] = __builtin_amdgcn_mfma_f32_16x16x32_bf16(pf1, vf1, o[di], 0, 0, 0);
        }
    }

    #pragma unroll
    for (int j = 0; j < 4; j++) {
        int qgj = qg + j;
        if (qgj >= Tn) continue;
        float inv = 1.0f / sume[j];
        #pragma unroll
        for (int di = 0; di < 4; di++)
            out[(size_t)(b*Tn + qgj) * Dn + h*64 + di*16 + l16] = f2bf(o[di][j] * inv);
    }
}

// ---------------- final fc on last position ----------------
__global__ __launch_bounds__(256) void fc_kernel(
    const float* __restrict__ x, const float* __restrict__ w,
    const float* __restrict__ bias, float* __restrict__ out)
{
    __shared__ float xs[Dn];
    int b = blockIdx.y;
    int v = blockIdx.x * 256 + threadIdx.x;
    float4 t = ((const float4*)(x + (size_t)(b*Tn + Tn - 1) * Dn))[threadIdx.x];
    ((float4*)xs)[threadIdx.x] = t;
    __syncthreads();
    float acc = bias[v];
    for (int d = 0; d < Dn; d++)
        acc = fmaf(xs[d], w[(size_t)d * Vn + v], acc);
    out[(size_t)b * Vn + v] = acc;
}

extern "C" void kernel_launch(void* const* d_in, const int* in_sizes, int n_in,
                              void* d_out, int out_size, void* d_ws, size_t ws_size,
                              hipStream_t stream)
{
    const int*   text_ids  = (const int*)d_in[0];
    const int*   prompt_ids= (const int*)d_in[1];
    const int*   output_ids= (const int*)d_in[2];
    const float* text_tab  = (const float*)d_in[3];
    const float* prompt_tab= (const float*)d_in[4];
    const float* output_tab= (const float*)d_in[5];
    const float* sep       = (const float*)d_in[6];
    const float* ln1_g     = (const float*)d_in[7];
    const float* ln1_b     = (const float*)d_in[8];
    const float* qkv_w     = (const float*)d_in[9];
    const float* out_w     = (const float*)d_in[10];
    const float* out_b     = (const float*)d_in[11];
    const float* ln2_g     = (const float*)d_in[12];
    const float* ln2_b     = (const float*)d_in[13];
    const float* ff1_w     = (const float*)d_in[14];
    const float* ff1_b     = (const float*)d_in[15];
    const float* ff2_w     = (const float*)d_in[16];
    const float* ff2_b     = (const float*)d_in[17];
    const float* fc_w      = (const float*)d_in[18];
    const float* fc_b      = (const float*)d_in[19];

    char* ws = (char*)d_ws;
    float*  x    = (float*)(ws);                    // [7184][1024] f32 = 29,425,664
    ushort* h    = (ushort*)(ws + 29425664);        // [7424][1024] bf16 = 15,204,352
    ushort* qkv  = (ushort*)(ws + 44630016);        // [7424][3072] bf16 = 45,613,056
    ushort* attn = (ushort*)(ws + 90243072);        // [7424][1024] bf16 = 15,204,352
    ushort* ff1o = (ushort*)(ws + 105447424);       // [7424][4096] bf16 = 60,817,408
    ushort* wT   = (ushort*)(ws + 166264832);       // weights bf16 [N][K]

    const size_t L_STRIDE = 12582912;        // ushorts per layer block
    const size_t OFF_QKV = 0, OFF_OUT = 3145728, OFF_FF1 = 4194304, OFF_FF2 = 8388608;
    const size_t upfront_need = 166264832ULL + 2ULL * L_STRIDE * Ln;
    const bool upfront = ws_size >= upfront_need;

    if (upfront) {
        transpose_cast_kernel<<<dim3(48,16,Ln), 256, 0, stream>>>(qkv_w, wT + OFF_QKV, Dn, 3*Dn, (size_t)Dn*3*Dn, L_STRIDE);
        transpose_cast_kernel<<<dim3(16,16,Ln), 256, 0, stream>>>(out_w, wT + OFF_OUT, Dn, Dn,   (size_t)Dn*Dn,   L_STRIDE);
        transpose_cast_kernel<<<dim3(64,16,Ln), 256, 0, stream>>>(ff1_w, wT + OFF_FF1, Dn, FFn,  (size_t)Dn*FFn,  L_STRIDE);
        transpose_cast_kernel<<<dim3(16,64,Ln), 256, 0, stream>>>(ff2_w, wT + OFF_FF2, FFn, Dn,  (size_t)FFn*Dn,  L_STRIDE);
    }

    embed_kernel<<<BT, 256, 0, stream>>>(text_ids, prompt_ids, output_ids,
                                         text_tab, prompt_tab, output_tab, sep, x);

    for (int l = 0; l < Ln; l++) {
        ushort* wb = upfront ? (wT + (size_t)l * L_STRIDE) : wT;
        if (!upfront) {
            transpose_cast_kernel<<<dim3(48,16,1), 256, 0, stream>>>(qkv_w + (size_t)l*Dn*3*Dn, wb + OFF_QKV, Dn, 3*Dn, 0, 0);
            transpose_cast_kernel<<<dim3(16,16,1), 256, 0, stream>>>(out_w + (size_t)l*Dn*Dn,   wb + OFF_OUT, Dn, Dn,   0, 0);
            transpose_cast_kernel<<<dim3(64,16,1), 256, 0, stream>>>(ff1_w + (size_t)l*Dn*FFn,  wb + OFF_FF1, Dn, FFn,  0, 0);
            transpose_cast_kernel<<<dim3(16,64,1), 256, 0, stream>>>(ff2_w + (size_t)l*FFn*Dn,  wb + OFF_FF2, FFn, Dn,  0, 0);
        }
        ln_kernel<<<BT, 256, 0, stream>>>(x, ln1_g + l*Dn, ln1_b + l*Dn, h);
        gemm3_kernel<0><<<57*24, 256, 0, stream>>>(
            h, wb + OFF_QKV, nullptr, nullptr, qkv, BT, 3*Dn, Dn, 24);
        attn_kernel<<<dim3(15, Bn, Hn), 256, 0, stream>>>(qkv, attn);
        gemm3_kernel<1><<<57*8, 256, 0, stream>>>(
            attn, wb + OFF_OUT, out_b + l*Dn, x, x, BT, Dn, Dn, 8);
        ln_kernel<<<BT, 256, 0, stream>>>(x, ln2_g + l*Dn, ln2_b + l*Dn, h);
        gemm3_kernel<2><<<57*32, 256, 0, stream>>>(
            h, wb + OFF_FF1, ff1_b + l*FFn, nullptr, ff1o, BT, FFn, Dn, 32);
        gemm3_kernel<1><<<57*8, 256, 0, stream>>>(
            ff1o, wb + OFF_FF2, ff2_b + l*Dn, x, x, BT, Dn, FFn, 8);
    }

    fc_kernel<<<dim3(Vn/256, Bn), 256, 0, stream>>>(x, fc_w, fc_b, (float*)d_out);
}

// Round 7
// 5360.481 us; speedup vs baseline: 1.1583x; 1.1583x over previous
//
#include <hip/hip_runtime.h>
#include <hip/hip_bf16.h>
#include <math.h>

#define Bn 8
#define Tn 898
#define Dn 1024
#define Hn 16
#define DHn 64
#define Ln 12
#define FFn 4096
#define Vn 1024
#define BT (Bn*Tn)   /* 7184 */

typedef short bf16x8 __attribute__((ext_vector_type(8)));
typedef float f32x4 __attribute__((ext_vector_type(4)));

__device__ __forceinline__ ushort f2bf(float f) {
    union { float f; unsigned u; } c; c.f = f;
    unsigned r = c.u + 0x7fffu + ((c.u >> 16) & 1u);
    return (ushort)(r >> 16);
}

__device__ __forceinline__ void glds16(const void* g, void* l) {
    __builtin_amdgcn_global_load_lds(
        (const __attribute__((address_space(1))) unsigned int*)g,
        (__attribute__((address_space(3))) unsigned int*)l, 16, 0, 0);
}

// ---------------- weight transpose + cast: f32 [K][N] -> bf16 [N][K] ----------------
__global__ __launch_bounds__(256) void transpose_cast_kernel(
    const float* __restrict__ in, ushort* __restrict__ out,
    int K, int N, size_t in_ls, size_t out_ls)
{
    __shared__ ushort t[64][68];
    const float* inp = in + (size_t)blockIdx.z * in_ls;
    ushort* outp = out + (size_t)blockIdx.z * out_ls;
    int n0 = blockIdx.x * 64, k0 = blockIdx.y * 64;
    int tx = threadIdx.x & 63, ty = threadIdx.x >> 6;
    #pragma unroll
    for (int p = 0; p < 16; p++) {
        int kl = p * 4 + ty;
        t[tx][kl] = f2bf(inp[(size_t)(k0 + kl) * N + n0 + tx]);
    }
    __syncthreads();
    int tx4 = threadIdx.x & 15, ty4 = threadIdx.x >> 4;
    #pragma unroll
    for (int p = 0; p < 4; p++) {
        int nl = p * 16 + ty4;
        ushort4 v;
        v.x = t[nl][4*tx4]; v.y = t[nl][4*tx4+1]; v.z = t[nl][4*tx4+2]; v.w = t[nl][4*tx4+3];
        *(ushort4*)&outp[(size_t)(n0 + nl) * K + k0 + 4*tx4] = v;
    }
}

// ---------------- embedding + positional encoding ----------------
__global__ __launch_bounds__(256) void embed_kernel(
    const int* __restrict__ tids, const int* __restrict__ pids, const int* __restrict__ oids,
    const float* __restrict__ ttab, const float* __restrict__ ptab, const float* __restrict__ otab,
    const float* __restrict__ sep, float* __restrict__ x)
{
    int bp = blockIdx.x;
    int b = bp / Tn, pos = bp - b * Tn;
    int d0 = threadIdx.x * 4;
    float4 r;
    if (pos == 128 || pos == 385) {
        r = *(const float4*)(sep + d0);
    } else {
        int t; int id; const float* tab;
        if (pos < 128)      { t = pos;       id = tids[b*128 + t]; tab = ttab; }
        else if (pos < 385) { t = pos - 129; id = pids[b*256 + t]; tab = ptab; }
        else                { t = pos - 386; id = oids[b*512 + t]; tab = otab; }
        float4 e = *(const float4*)(tab + (size_t)id * Dn + d0);
        float pe[4];
        #pragma unroll
        for (int i = 0; i < 4; i++) {
            int d = d0 + i;
            int ii = d & 511;
            float omega = expf(-9.210340371976184f * (float)ii * (1.0f/512.0f));
            float ang = (float)t * omega;
            pe[i] = (d < 512) ? sinf(ang) : cosf(ang);
        }
        r.x = e.x + pe[0]; r.y = e.y + pe[1]; r.z = e.z + pe[2]; r.w = e.w + pe[3];
    }
    *(float4*)(x + (size_t)bp * Dn + d0) = r;
}

// ---------------- layernorm fp32 -> bf16 ----------------
__global__ __launch_bounds__(256) void ln_kernel(
    const float* __restrict__ x, const float* __restrict__ g, const float* __restrict__ bt,
    ushort* __restrict__ out)
{
    __shared__ float red[8];
    int row = blockIdx.x, tid = threadIdx.x;
    float4 v = ((const float4*)(x + (size_t)row * Dn))[tid];
    float s = v.x + v.y + v.z + v.w;
    #pragma unroll
    for (int o = 32; o; o >>= 1) s += __shfl_down(s, o);
    if ((tid & 63) == 0) red[tid >> 6] = s;
    __syncthreads();
    float mu = (red[0] + red[1] + red[2] + red[3]) * (1.0f / Dn);
    float d0 = v.x - mu, d1 = v.y - mu, d2 = v.z - mu, d3 = v.w - mu;
    float s2 = d0*d0 + d1*d1 + d2*d2 + d3*d3;
    #pragma unroll
    for (int o = 32; o; o >>= 1) s2 += __shfl_down(s2, o);
    if ((tid & 63) == 0) red[4 + (tid >> 6)] = s2;
    __syncthreads();
    float var = (red[4] + red[5] + red[6] + red[7]) * (1.0f / Dn);
    float rstd = rsqrtf(var + 1e-5f);
    float4 gg = ((const float4*)g)[tid];
    float4 bb = ((const float4*)bt)[tid];
    ushort4 o4;
    o4.x = f2bf(d0 * rstd * gg.x + bb.x);
    o4.y = f2bf(d1 * rstd * gg.y + bb.y);
    o4.z = f2bf(d2 * rstd * gg.z + bb.z);
    o4.w = f2bf(d3 * rstd * gg.w + bb.w);
    ((ushort4*)(out + (size_t)row * Dn))[tid] = o4;
}

// ---------------- m97-style GEMM, max-residency: C = A(bf16 [M][K]) @ Bw(bf16 [N][K])^T ----
// 128xBN tile (BN = 128 or 64), 4 waves, BK=32, SINGLE 16KB/12KB LDS buffer ->
// many blocks/CU (cross-block TLP hides staging; proven fastest of R2-R6).
// Correct 2-way-free LDS swizzle for 64B rows: chunk ^= (row>>1)&3, applied to
// glds SOURCE (LDS dest stays linear) and to ds_read addresses.
// MODE 0: store bf16; MODE 1: f32 = resid + AB + bias; MODE 2: bf16 = gelu(AB + bias)
template<int BN, int MODE>
__global__ __launch_bounds__(256) void gemmk(
    const ushort* __restrict__ A, const ushort* __restrict__ Bw,
    const float* __restrict__ bias, const float* __restrict__ resid,
    void* __restrict__ Cout, int M, int N, int K, int nx)
{
    constexpr int NI = BN / 32;          // frags per wave in N: 4 (BN=128) or 2 (BN=64)
    __shared__ ushort sA[128 * 32];
    __shared__ ushort sB[BN * 32];

    int tid = threadIdx.x, lane = tid & 63, wv = tid >> 6;
    int wm = wv >> 1, wn = wv & 1;
    int l16 = lane & 15, lhi = lane >> 4;

    // bijective XCD-chunked swizzle
    int nb = gridDim.x, bid = blockIdx.x;
    int qq = nb >> 3, rr8 = nb & 7;
    int xcd = bid & 7, idx = bid >> 3;
    int wg = (xcd < rr8 ? xcd * (qq + 1) : rr8 * (qq + 1) + (xcd - rr8) * qq) + idx;
    int mt = wg / nx, ntt = wg - mt * nx;
    int m0 = mt * 128, n0 = ntt * BN;

    f32x4 acc[4][NI];
    #pragma unroll
    for (int i = 0; i < 4; i++)
        #pragma unroll
        for (int j = 0; j < NI; j++) acc[i][j] = (f32x4){0.f, 0.f, 0.f, 0.f};

    // staging: each glds16 covers one 16-row unit (16 rows x 64B).
    // lane -> row (lane>>2), LDS chunk (lane&3); source chunk XOR'd by (row>>1)&3 = (lane>>3)&3.
    const size_t K2 = (size_t)K * 2;
    int srow = lane >> 2;
    int schk = ((lane & 3) ^ ((lane >> 3) & 3)) * 16;
    const char* Abase = (const char*)A + (size_t)m0 * K2 + schk;
    const char* Bbase = (const char*)Bw + (size_t)n0 * K2 + schk;

    auto stage = [&](int t) {
        size_t ko = (size_t)t * 64;
        glds16(Abase + (size_t)(wv * 16 + srow) * K2 + ko,       (char*)sA + wv * 1024);
        glds16(Abase + (size_t)((wv + 4) * 16 + srow) * K2 + ko, (char*)sA + (wv + 4) * 1024);
        glds16(Bbase + (size_t)(wv * 16 + srow) * K2 + ko,       (char*)sB + wv * 1024);
        if (BN == 128)
            glds16(Bbase + (size_t)((wv + 4) * 16 + srow) * K2 + ko, (char*)sB + (wv + 4) * 1024);
    };

    // fragment reads: swizzled chunk = lhi ^ ((row>>1)&3); row>>1&3 == (l16>>1)&3 for all frag rows
    const int sc = (lhi ^ ((l16 >> 1) & 3)) * 8;
    auto compute = [&]() {
        bf16x8 af[4], bf[NI];
        #pragma unroll
        for (int mi = 0; mi < 4; mi++)
            af[mi] = *(const bf16x8*)&sA[(wm * 64 + mi * 16 + l16) * 32 + sc];
        #pragma unroll
        for (int ni = 0; ni < NI; ni++)
            bf[ni] = *(const bf16x8*)&sB[(wn * (16 * NI) + ni * 16 + l16) * 32 + sc];
        #pragma unroll
        for (int mi = 0; mi < 4; mi++)
            #pragma unroll
            for (int ni = 0; ni < NI; ni++)
                acc[mi][ni] = __builtin_amdgcn_mfma_f32_16x16x32_bf16(af[mi], bf[ni], acc[mi][ni], 0, 0, 0);
    };

    int ntile = K >> 5;
    for (int t = 0; t < ntile; ++t) {
        __syncthreads();   // prev compute's LDS reads done before overwrite
        stage(t);
        __syncthreads();   // vmcnt(0) drain + barrier (compiler-inserted)
        compute();
    }

    // epilogue
    #pragma unroll
    for (int mi = 0; mi < 4; mi++) {
        int rl = wm * 64 + mi * 16 + lhi * 4;
        #pragma unroll
        for (int ni = 0; ni < NI; ni++) {
            int gcol = n0 + wn * (16 * NI) + ni * 16 + l16;
            float bs = (MODE == 0) ? 0.0f : bias[gcol];
            #pragma unroll
            for (int j = 0; j < 4; j++) {
                int grow = m0 + rl + j;
                if (grow >= M) continue;
                float v = acc[mi][ni][j] + bs;
                if (MODE == 1) {
                    float rv = resid[(size_t)grow * N + gcol];
                    ((float*)Cout)[(size_t)grow * N + gcol] = rv + v;
                } else if (MODE == 2) {
                    // gelu(v) ~= v * sigmoid(1.5957691216 v + 0.0713548163 v^3)  (tanh form, |err|<~3e-4)
                    float u = v * (1.5957691216f + 0.0713548163f * v * v);
                    float g = v / (1.0f + __expf(-u));
                    ((ushort*)Cout)[(size_t)grow * N + gcol] = f2bf(g);
                } else {
                    ((ushort*)Cout)[(size_t)grow * N + gcol] = f2bf(v);
                }
            }
        }
    }
}

// ---------------- flash attention (causal), bf16 in/out ----------------
__global__ __launch_bounds__(256) void attn_kernel(
    const ushort* __restrict__ qkv, ushort* __restrict__ out)
{
    __shared__ ushort Ksm[64 * 72];
    __shared__ ushort Vsm[64 * 72];
    __shared__ ushort Psm[4][16 * 72];
    int qt = blockIdx.x, b = blockIdx.y, h = blockIdx.z;
    int tid = threadIdx.x, lane = tid & 63, wave = tid >> 6;
    int l16 = lane & 15, lhi = lane >> 4;

    int qrow = qt*64 + wave*16 + l16;
    bf16x8 qf0 = {}, qf1 = {};
    if (qrow < Tn) {
        const ushort* qp = qkv + (size_t)(b*Tn + qrow) * 3072 + h*64 + lhi*8;
        qf0 = *(const bf16x8*)qp;
        qf1 = *(const bf16x8*)(qp + 32);
    }

    f32x4 o[4];
    #pragma unroll
    for (int i = 0; i < 4; i++) o[i] = (f32x4){0.f,0.f,0.f,0.f};
    float mrun[4] = {-1e30f,-1e30f,-1e30f,-1e30f};
    float sume[4] = {0.f,0.f,0.f,0.f};

    int kr = tid >> 2, cc = (tid & 3) * 16;
    const ushort* kvbase = qkv + (size_t)(b*Tn) * 3072 + h*64 + cc;
    int qg = qt*64 + wave*16 + lhi*4;

    for (int jt = 0; jt <= qt; jt++) {
        int kvr = jt*64 + kr;
        uint4 k0 = make_uint4(0,0,0,0), k1 = k0, v0 = k0, v1 = k0;
        if (kvr < Tn) {
            const ushort* p = kvbase + (size_t)kvr * 3072;
            k0 = *(const uint4*)(p + 1024);
            k1 = *(const uint4*)(p + 1024 + 8);
            v0 = *(const uint4*)(p + 2048);
            v1 = *(const uint4*)(p + 2048 + 8);
        }
        __syncthreads();
        *(uint4*)&Ksm[kr * 72 + cc] = k0;
        *(uint4*)&Ksm[kr * 72 + cc + 8] = k1;
        {
            ushort vv[16];
            *(uint4*)&vv[0] = v0; *(uint4*)&vv[8] = v1;
            #pragma unroll
            for (int i = 0; i < 16; i++) Vsm[(cc + i) * 72 + kr] = vv[i];
        }
        __syncthreads();

        f32x4 s[4];
        #pragma unroll
        for (int ni = 0; ni < 4; ni++) {
            s[ni] = (f32x4){0.f,0.f,0.f,0.f};
            bf16x8 kf0 = *(const bf16x8*)&Ksm[(ni*16 + l16) * 72 + lhi*8];
            bf16x8 kf1 = *(const bf16x8*)&Ksm[(ni*16 + l16) * 72 + lhi*8 + 32];
            s[ni] = __builtin_amdgcn_mfma_f32_16x16x32_bf16(qf0, kf0, s[ni], 0, 0, 0);
            s[ni] = __builtin_amdgcn_mfma_f32_16x16x32_bf16(qf1, kf1, s[ni], 0, 0, 0);
        }

        float pv[4][4];
        #pragma unroll
        for (int j = 0; j < 4; j++) {
            int qgj = qg + j;
            float mx = -1e30f;
            #pragma unroll
            for (int ni = 0; ni < 4; ni++) {
                int kvg = jt*64 + ni*16 + l16;
                float e = (kvg <= qgj && kvg < Tn) ? s[ni][j] * 0.125f : -1e30f;
                pv[ni][j] = e;
                mx = fmaxf(mx, e);
            }
            #pragma unroll
            for (int m = 1; m < 16; m <<= 1) mx = fmaxf(mx, __shfl_xor(mx, m));
            float mnew = fmaxf(mrun[j], mx);
            float fac = expf(mrun[j] - mnew);
            mrun[j] = mnew;
            float rs = 0.f;
            #pragma unroll
            for (int ni = 0; ni < 4; ni++) { pv[ni][j] = expf(pv[ni][j] - mnew); rs += pv[ni][j]; }
            #pragma unroll
            for (int m = 1; m < 16; m <<= 1) rs += __shfl_xor(rs, m);
            sume[j] = sume[j] * fac + rs;
            #pragma unroll
            for (int di = 0; di < 4; di++) o[di][j] *= fac;
        }

        #pragma unroll
        for (int j = 0; j < 4; j++)
            #pragma unroll
            for (int ni = 0; ni < 4; ni++)
                Psm[wave][(lhi*4 + j) * 72 + ni*16 + l16] = f2bf(pv[ni][j]);
        __syncthreads();

        bf16x8 pf0 = *(const bf16x8*)&Psm[wave][l16 * 72 + lhi*8];
        bf16x8 pf1 = *(const bf16x8*)&Psm[wave][l16 * 72 + lhi*8 + 32];
        #pragma unroll
        for (int di = 0; di < 4; di++) {
            bf16x8 vf0 = *(const bf16x8*)&Vsm[(di*16 + l16) * 72 + lhi*8];
            bf16x8 vf1 = *(const bf16x8*)&Vsm[(di*16 + l16) * 72 + lhi*8 + 32];
            o[di] = __builtin_amdgcn_mfma_f32_16x16x32_bf16(pf0, vf0, o[di], 0, 0, 0);
            o[di] = __builtin_amdgcn_mfma_f32_16x16x32_bf16(pf1, vf1, o[di], 0, 0, 0);
        }
    }

    #pragma unroll
    for (int j = 0; j < 4; j++) {
        int qgj = qg + j;
        if (qgj >= Tn) continue;
        float inv = 1.0f / sume[j];
        #pragma unroll
        for (int di = 0; di < 4; di++)
            out[(size_t)(b*Tn + qgj) * Dn + h*64 + di*16 + l16] = f2bf(o[di][j] * inv);
    }
}

// ---------------- final fc on last position ----------------
__global__ __launch_bounds__(256) void fc_kernel(
    const float* __restrict__ x, const float* __restrict__ w,
    const float* __restrict__ bias, float* __restrict__ out)
{
    __shared__ float xs[Dn];
    int b = blockIdx.y;
    int v = blockIdx.x * 256 + threadIdx.x;
    float4 t = ((const float4*)(x + (size_t)(b*Tn + Tn - 1) * Dn))[threadIdx.x];
    ((float4*)xs)[threadIdx.x] = t;
    __syncthreads();
    float acc = bias[v];
    for (int d = 0; d < Dn; d++)
        acc = fmaf(xs[d], w[(size_t)d * Vn + v], acc);
    out[(size_t)b * Vn + v] = acc;
}

extern "C" void kernel_launch(void* const* d_in, const int* in_sizes, int n_in,
                              void* d_out, int out_size, void* d_ws, size_t ws_size,
                              hipStream_t stream)
{
    const int*   text_ids  = (const int*)d_in[0];
    const int*   prompt_ids= (const int*)d_in[1];
    const int*   output_ids= (const int*)d_in[2];
    const float* text_tab  = (const float*)d_in[3];
    const float* prompt_tab= (const float*)d_in[4];
    const float* output_tab= (const float*)d_in[5];
    const float* sep       = (const float*)d_in[6];
    const float* ln1_g     = (const float*)d_in[7];
    const float* ln1_b     = (const float*)d_in[8];
    const float* qkv_w     = (const float*)d_in[9];
    const float* out_w     = (const float*)d_in[10];
    const float* out_b     = (const float*)d_in[11];
    const float* ln2_g     = (const float*)d_in[12];
    const float* ln2_b     = (const float*)d_in[13];
    const float* ff1_w     = (const float*)d_in[14];
    const float* ff1_b     = (const float*)d_in[15];
    const float* ff2_w     = (const float*)d_in[16];
    const float* ff2_b     = (const float*)d_in[17];
    const float* fc_w      = (const float*)d_in[18];
    const float* fc_b      = (const float*)d_in[19];

    char* ws = (char*)d_ws;
    float*  x    = (float*)(ws);                    // [7184][1024] f32 = 29,425,664
    ushort* h    = (ushort*)(ws + 29425664);        // [7424][1024] bf16 = 15,204,352
    ushort* qkv  = (ushort*)(ws + 44630016);        // [7424][3072] bf16 = 45,613,056
    ushort* attn = (ushort*)(ws + 90243072);        // [7424][1024] bf16 = 15,204,352
    ushort* ff1o = (ushort*)(ws + 105447424);       // [7424][4096] bf16 = 60,817,408
    ushort* wT   = (ushort*)(ws + 166264832);       // weights bf16 [N][K]

    const size_t L_STRIDE = 12582912;        // ushorts per layer block
    const size_t OFF_QKV = 0, OFF_OUT = 3145728, OFF_FF1 = 4194304, OFF_FF2 = 8388608;
    const size_t upfront_need = 166264832ULL + 2ULL * L_STRIDE * Ln;
    const bool upfront = ws_size >= upfront_need;

    if (upfront) {
        transpose_cast_kernel<<<dim3(48,16,Ln), 256, 0, stream>>>(qkv_w, wT + OFF_QKV, Dn, 3*Dn, (size_t)Dn*3*Dn, L_STRIDE);
        transpose_cast_kernel<<<dim3(16,16,Ln), 256, 0, stream>>>(out_w, wT + OFF_OUT, Dn, Dn,   (size_t)Dn*Dn,   L_STRIDE);
        transpose_cast_kernel<<<dim3(64,16,Ln), 256, 0, stream>>>(ff1_w, wT + OFF_FF1, Dn, FFn,  (size_t)Dn*FFn,  L_STRIDE);
        transpose_cast_kernel<<<dim3(16,64,Ln), 256, 0, stream>>>(ff2_w, wT + OFF_FF2, FFn, Dn,  (size_t)FFn*Dn,  L_STRIDE);
    }

    embed_kernel<<<BT, 256, 0, stream>>>(text_ids, prompt_ids, output_ids,
                                         text_tab, prompt_tab, output_tab, sep, x);

    for (int l = 0; l < Ln; l++) {
        ushort* wb = upfront ? (wT + (size_t)l * L_STRIDE) : wT;
        if (!upfront) {
            transpose_cast_kernel<<<dim3(48,16,1), 256, 0, stream>>>(qkv_w + (size_t)l*Dn*3*Dn, wb + OFF_QKV, Dn, 3*Dn, 0, 0);
            transpose_cast_kernel<<<dim3(16,16,1), 256, 0, stream>>>(out_w + (size_t)l*Dn*Dn,   wb + OFF_OUT, Dn, Dn,   0, 0);
            transpose_cast_kernel<<<dim3(64,16,1), 256, 0, stream>>>(ff1_w + (size_t)l*Dn*FFn,  wb + OFF_FF1, Dn, FFn,  0, 0);
            transpose_cast_kernel<<<dim3(16,64,1), 256, 0, stream>>>(ff2_w + (size_t)l*FFn*Dn,  wb + OFF_FF2, FFn, Dn,  0, 0);
        }
        ln_kernel<<<BT, 256, 0, stream>>>(x, ln1_g + l*Dn, ln1_b + l*Dn, h);
        gemmk<128,0><<<57*24, 256, 0, stream>>>(
            h, wb + OFF_QKV, nullptr, nullptr, qkv, BT, 3*Dn, Dn, 24);
        attn_kernel<<<dim3(15, Bn, Hn), 256, 0, stream>>>(qkv, attn);
        gemmk<64,1><<<57*16, 256, 0, stream>>>(
            attn, wb + OFF_OUT, out_b + l*Dn, x, x, BT, Dn, Dn, 16);
        ln_kernel<<<BT, 256, 0, stream>>>(x, ln2_g + l*Dn, ln2_b + l*Dn, h);
        gemmk<128,2><<<57*32, 256, 0, stream>>>(
            h, wb + OFF_FF1, ff1_b + l*FFn, nullptr, ff1o, BT, FFn, Dn, 32);
        gemmk<64,1><<<57*16, 256, 0, stream>>>(
            ff1o, wb + OFF_FF2, ff2_b + l*Dn, x, x, BT, Dn, FFn, 16);
    }

    fc_kernel<<<dim3(Vn/256, Bn), 256, 0, stream>>>(x, fc_w, fc_b, (float*)d_out);
}

// Round 8
// 5144.146 us; speedup vs baseline: 1.2070x; 1.0421x over previous
//
#include <hip/hip_runtime.h>
#include <hip/hip_bf16.h>
#include <math.h>

#define Bn 8
#define Tn 898
#define Dn 1024
#define Hn 16
#define DHn 64
#define Ln 12
#define FFn 4096
#define Vn 1024
#define BT (Bn*Tn)   /* 7184 */

typedef short bf16x8 __attribute__((ext_vector_type(8)));
typedef float f32x4 __attribute__((ext_vector_type(4)));

__device__ __forceinline__ ushort f2bf(float f) {
    union { float f; unsigned u; } c; c.f = f;
    unsigned r = c.u + 0x7fffu + ((c.u >> 16) & 1u);
    return (ushort)(r >> 16);
}

__device__ __forceinline__ void glds16(const void* g, void* l) {
    __builtin_amdgcn_global_load_lds(
        (const __attribute__((address_space(1))) unsigned int*)g,
        (__attribute__((address_space(3))) unsigned int*)l, 16, 0, 0);
}

#define BARRIER() __builtin_amdgcn_s_barrier()
#define VMCNT0() asm volatile("s_waitcnt vmcnt(0)" ::: "memory")

// ---------------- weight transpose + cast: f32 [K][N] -> bf16 [N][K] ----------------
__global__ __launch_bounds__(256) void transpose_cast_kernel(
    const float* __restrict__ in, ushort* __restrict__ out,
    int K, int N, size_t in_ls, size_t out_ls)
{
    __shared__ ushort t[64][68];
    const float* inp = in + (size_t)blockIdx.z * in_ls;
    ushort* outp = out + (size_t)blockIdx.z * out_ls;
    int n0 = blockIdx.x * 64, k0 = blockIdx.y * 64;
    int tx = threadIdx.x & 63, ty = threadIdx.x >> 6;
    #pragma unroll
    for (int p = 0; p < 16; p++) {
        int kl = p * 4 + ty;
        t[tx][kl] = f2bf(inp[(size_t)(k0 + kl) * N + n0 + tx]);
    }
    __syncthreads();
    int tx4 = threadIdx.x & 15, ty4 = threadIdx.x >> 4;
    #pragma unroll
    for (int p = 0; p < 4; p++) {
        int nl = p * 16 + ty4;
        ushort4 v;
        v.x = t[nl][4*tx4]; v.y = t[nl][4*tx4+1]; v.z = t[nl][4*tx4+2]; v.w = t[nl][4*tx4+3];
        *(ushort4*)&outp[(size_t)(n0 + nl) * K + k0 + 4*tx4] = v;
    }
}

// ---------------- embedding + positional encoding ----------------
__global__ __launch_bounds__(256) void embed_kernel(
    const int* __restrict__ tids, const int* __restrict__ pids, const int* __restrict__ oids,
    const float* __restrict__ ttab, const float* __restrict__ ptab, const float* __restrict__ otab,
    const float* __restrict__ sep, float* __restrict__ x)
{
    int bp = blockIdx.x;
    int b = bp / Tn, pos = bp - b * Tn;
    int d0 = threadIdx.x * 4;
    float4 r;
    if (pos == 128 || pos == 385) {
        r = *(const float4*)(sep + d0);
    } else {
        int t; int id; const float* tab;
        if (pos < 128)      { t = pos;       id = tids[b*128 + t]; tab = ttab; }
        else if (pos < 385) { t = pos - 129; id = pids[b*256 + t]; tab = ptab; }
        else                { t = pos - 386; id = oids[b*512 + t]; tab = otab; }
        float4 e = *(const float4*)(tab + (size_t)id * Dn + d0);
        float pe[4];
        #pragma unroll
        for (int i = 0; i < 4; i++) {
            int d = d0 + i;
            int ii = d & 511;
            float omega = expf(-9.210340371976184f * (float)ii * (1.0f/512.0f));
            float ang = (float)t * omega;
            pe[i] = (d < 512) ? sinf(ang) : cosf(ang);
        }
        r.x = e.x + pe[0]; r.y = e.y + pe[1]; r.z = e.z + pe[2]; r.w = e.w + pe[3];
    }
    *(float4*)(x + (size_t)bp * Dn + d0) = r;
}

// ---------------- layernorm fp32 -> bf16, one row per WAVE (no LDS, no barrier) ----------
__global__ __launch_bounds__(256) void ln_kernel(
    const float* __restrict__ x, const float* __restrict__ g, const float* __restrict__ bt,
    ushort* __restrict__ out)
{
    int row = blockIdx.x * 4 + (threadIdx.x >> 6);
    int lane = threadIdx.x & 63;
    const float4* xr = (const float4*)(x + (size_t)row * Dn);
    float4 v[4];
    float s = 0.f;
    #pragma unroll
    for (int i = 0; i < 4; i++) {
        v[i] = xr[lane + 64 * i];
        s += v[i].x + v[i].y + v[i].z + v[i].w;
    }
    #pragma unroll
    for (int o = 32; o; o >>= 1) s += __shfl_xor(s, o);
    float mu = s * (1.0f / Dn);
    float s2 = 0.f;
    #pragma unroll
    for (int i = 0; i < 4; i++) {
        v[i].x -= mu; v[i].y -= mu; v[i].z -= mu; v[i].w -= mu;
        s2 += v[i].x*v[i].x + v[i].y*v[i].y + v[i].z*v[i].z + v[i].w*v[i].w;
    }
    #pragma unroll
    for (int o = 32; o; o >>= 1) s2 += __shfl_xor(s2, o);
    float rstd = rsqrtf(s2 * (1.0f / Dn) + 1e-5f);
    ushort4* orow = (ushort4*)(out + (size_t)row * Dn);
    #pragma unroll
    for (int i = 0; i < 4; i++) {
        float4 gg = ((const float4*)g)[lane + 64 * i];
        float4 bb = ((const float4*)bt)[lane + 64 * i];
        ushort4 o4;
        o4.x = f2bf(v[i].x * rstd * gg.x + bb.x);
        o4.y = f2bf(v[i].y * rstd * gg.y + bb.y);
        o4.z = f2bf(v[i].z * rstd * gg.z + bb.z);
        o4.w = f2bf(v[i].w * rstd * gg.w + bb.w);
        orow[lane + 64 * i] = o4;
    }
}

// ---------------- 2-phase double-buffered GEMM (T3 minimum recipe) -------------------------
// C = A(bf16 [M][K]) @ Bw(bf16 [N][K])^T. 128xBN tile, 4 waves, BK=32.
// STAGE(next buf) issued BEFORE ds_read+MFMA of current buf; one vmcnt(0)+barrier per tile.
// 2-way-free LDS swizzle for 64B rows (chunk ^= (row>>1)&3) on glds SOURCE + ds_read addr.
// MODE 0: store bf16; MODE 1: f32 = resid + AB + bias; MODE 2: bf16 = gelu(AB + bias)
template<int BN, int MODE>
__global__ __launch_bounds__(256) void gemmk(
    const ushort* __restrict__ A, const ushort* __restrict__ Bw,
    const float* __restrict__ bias, const float* __restrict__ resid,
    void* __restrict__ Cout, int M, int N, int K, int nx)
{
    constexpr int NI = BN / 32;          // frags per wave in N: 4 (BN=128) or 2 (BN=64)
    __shared__ ushort sA[2][128 * 32];
    __shared__ ushort sB[2][BN * 32];

    int tid = threadIdx.x, lane = tid & 63, wv = tid >> 6;
    int wm = wv >> 1, wn = wv & 1;
    int l16 = lane & 15, lhi = lane >> 4;

    // bijective XCD-chunked swizzle
    int nb = gridDim.x, bid = blockIdx.x;
    int qq = nb >> 3, rr8 = nb & 7;
    int xcd = bid & 7, idx = bid >> 3;
    int wg = (xcd < rr8 ? xcd * (qq + 1) : rr8 * (qq + 1) + (xcd - rr8) * qq) + idx;
    int mt = wg / nx, ntt = wg - mt * nx;
    int m0 = mt * 128, n0 = ntt * BN;

    f32x4 acc[4][NI];
    #pragma unroll
    for (int i = 0; i < 4; i++)
        #pragma unroll
        for (int j = 0; j < NI; j++) acc[i][j] = (f32x4){0.f, 0.f, 0.f, 0.f};

    // staging: each glds16 covers one 16-row unit (16 rows x 64B).
    // lane -> row (lane>>2), LDS chunk (lane&3); source chunk XOR'd by (row>>1)&3 = (lane>>3)&3.
    const size_t K2 = (size_t)K * 2;
    int srow = lane >> 2;
    int schk = ((lane & 3) ^ ((lane >> 3) & 3)) * 16;
    const char* Aw0 = (const char*)A + (size_t)(m0 + wv * 16 + srow) * K2 + schk;
    const char* Aw1 = (const char*)A + (size_t)(m0 + (wv + 4) * 16 + srow) * K2 + schk;
    const char* Bp0 = (const char*)Bw + (size_t)(n0 + wv * 16 + srow) * K2 + schk;
    const char* Bp1 = (BN == 128) ? (const char*)Bw + (size_t)(n0 + (wv + 4) * 16 + srow) * K2 + schk : nullptr;

    auto stage = [&](int buf) {
        glds16(Aw0, (char*)sA[buf] + wv * 1024);
        glds16(Aw1, (char*)sA[buf] + (wv + 4) * 1024);
        glds16(Bp0, (char*)sB[buf] + wv * 1024);
        if (BN == 128)
            glds16(Bp1, (char*)sB[buf] + (wv + 4) * 1024);
        Aw0 += 64; Aw1 += 64; Bp0 += 64;
        if (BN == 128) Bp1 += 64;
    };

    // fragment reads: swizzled chunk = lhi ^ ((row>>1)&3); (row>>1)&3 == (l16>>1)&3 for all frag rows
    const int sc = (lhi ^ ((l16 >> 1) & 3)) * 8;
    auto compute = [&](int buf) {
        bf16x8 af[4], bf[NI];
        #pragma unroll
        for (int mi = 0; mi < 4; mi++)
            af[mi] = *(const bf16x8*)&sA[buf][(wm * 64 + mi * 16 + l16) * 32 + sc];
        #pragma unroll
        for (int ni = 0; ni < NI; ni++)
            bf[ni] = *(const bf16x8*)&sB[buf][(wn * (16 * NI) + ni * 16 + l16) * 32 + sc];
        #pragma unroll
        for (int mi = 0; mi < 4; mi++)
            #pragma unroll
            for (int ni = 0; ni < NI; ni++)
                acc[mi][ni] = __builtin_amdgcn_mfma_f32_16x16x32_bf16(af[mi], bf[ni], acc[mi][ni], 0, 0, 0);
    };

    int ntile = K >> 5;
    // prologue
    stage(0);
    VMCNT0();
    BARRIER();
    int cur = 0;
    for (int t = 0; t < ntile; ++t) {
        if (t + 1 < ntile) stage(cur ^ 1);   // issue next-tile loads FIRST (latency hides under MFMA)
        compute(cur);                        // ds_read + MFMA on current buffer
        VMCNT0();                            // staged writes landed
        BARRIER();                           // all waves' LDS reads done -> safe to overwrite
        cur ^= 1;
    }

    // epilogue
    #pragma unroll
    for (int mi = 0; mi < 4; mi++) {
        int rl = wm * 64 + mi * 16 + lhi * 4;
        #pragma unroll
        for (int ni = 0; ni < NI; ni++) {
            int gcol = n0 + wn * (16 * NI) + ni * 16 + l16;
            float bs = (MODE == 0) ? 0.0f : bias[gcol];
            #pragma unroll
            for (int j = 0; j < 4; j++) {
                int grow = m0 + rl + j;
                if (grow >= M) continue;
                float v = acc[mi][ni][j] + bs;
                if (MODE == 1) {
                    float rv = resid[(size_t)grow * N + gcol];
                    ((float*)Cout)[(size_t)grow * N + gcol] = rv + v;
                } else if (MODE == 2) {
                    // gelu(v) ~= v * sigmoid(1.5957691216 v + 0.0713548163 v^3)  (tanh form, |err|<~3e-4)
                    float u = v * (1.5957691216f + 0.0713548163f * v * v);
                    float g = v / (1.0f + __expf(-u));
                    ((ushort*)Cout)[(size_t)grow * N + gcol] = f2bf(g);
                } else {
                    ((ushort*)Cout)[(size_t)grow * N + gcol] = f2bf(v);
                }
            }
        }
    }
}

// ---------------- flash attention (causal), bf16 in/out ----------------
__global__ __launch_bounds__(256) void attn_kernel(
    const ushort* __restrict__ qkv, ushort* __restrict__ out)
{
    __shared__ ushort Ksm[64 * 72];
    __shared__ ushort Vsm[64 * 72];
    __shared__ ushort Psm[4][16 * 72];
    int qt = blockIdx.x, b = blockIdx.y, h = blockIdx.z;
    int tid = threadIdx.x, lane = tid & 63, wave = tid >> 6;
    int l16 = lane & 15, lhi = lane >> 4;

    int qrow = qt*64 + wave*16 + l16;
    bf16x8 qf0 = {}, qf1 = {};
    if (qrow < Tn) {
        const ushort* qp = qkv + (size_t)(b*Tn + qrow) * 3072 + h*64 + lhi*8;
        qf0 = *(const bf16x8*)qp;
        qf1 = *(const bf16x8*)(qp + 32);
    }

    f32x4 o[4];
    #pragma unroll
    for (int i = 0; i < 4; i++) o[i] = (f32x4){0.f,0.f,0.f,0.f};
    float mrun[4] = {-1e30f,-1e30f,-1e30f,-1e30f};
    float sume[4] = {0.f,0.f,0.f,0.f};

    int kr = tid >> 2, cc = (tid & 3) * 16;
    const ushort* kvbase = qkv + (size_t)(b*Tn) * 3072 + h*64 + cc;
    int qg = qt*64 + wave*16 + lhi*4;

    for (int jt = 0; jt <= qt; jt++) {
        int kvr = jt*64 + kr;
        uint4 k0 = make_uint4(0,0,0,0), k1 = k0, v0 = k0, v1 = k0;
        if (kvr < Tn) {
            const ushort* p = kvbase + (size_t)kvr * 3072;
            k0 = *(const uint4*)(p + 1024);
            k1 = *(const uint4*)(p + 1024 + 8);
            v0 = *(const uint4*)(p + 2048);
            v1 = *(const uint4*)(p + 2048 + 8);
        }
        __syncthreads();
        *(uint4*)&Ksm[kr * 72 + cc] = k0;
        *(uint4*)&Ksm[kr * 72 + cc + 8] = k1;
        {
            ushort vv[16];
            *(uint4*)&vv[0] = v0; *(uint4*)&vv[8] = v1;
            #pragma unroll
            for (int i = 0; i < 16; i++) Vsm[(cc + i) * 72 + kr] = vv[i];
        }
        __syncthreads();

        f32x4 s[4];
        #pragma unroll
        for (int ni = 0; ni < 4; ni++) {
            s[ni] = (f32x4){0.f,0.f,0.f,0.f};
            bf16x8 kf0 = *(const bf16x8*)&Ksm[(ni*16 + l16) * 72 + lhi*8];
            bf16x8 kf1 = *(const bf16x8*)&Ksm[(ni*16 + l16) * 72 + lhi*8 + 32];
            s[ni] = __builtin_amdgcn_mfma_f32_16x16x32_bf16(qf0, kf0, s[ni], 0, 0, 0);
            s[ni] = __builtin_amdgcn_mfma_f32_16x16x32_bf16(qf1, kf1, s[ni], 0, 0, 0);
        }

        float pv[4][4];
        #pragma unroll
        for (int j = 0; j < 4; j++) {
            int qgj = qg + j;
            float mx = -1e30f;
            #pragma unroll
            for (int ni = 0; ni < 4; ni++) {
                int kvg = jt*64 + ni*16 + l16;
                float e = (kvg <= qgj && kvg < Tn) ? s[ni][j] * 0.125f : -1e30f;
                pv[ni][j] = e;
                mx = fmaxf(mx, e);
            }
            #pragma unroll
            for (int m = 1; m < 16; m <<= 1) mx = fmaxf(mx, __shfl_xor(mx, m));
            float mnew = fmaxf(mrun[j], mx);
            float fac = expf(mrun[j] - mnew);
            mrun[j] = mnew;
            float rs = 0.f;
            #pragma unroll
            for (int ni = 0; ni < 4; ni++) { pv[ni][j] = expf(pv[ni][j] - mnew); rs += pv[ni][j]; }
            #pragma unroll
            for (int m = 1; m < 16; m <<= 1) rs += __shfl_xor(rs, m);
            sume[j] = sume[j] * fac + rs;
            #pragma unroll
            for (int di = 0; di < 4; di++) o[di][j] *= fac;
        }

        #pragma unroll
        for (int j = 0; j < 4; j++)
            #pragma unroll
            for (int ni = 0; ni < 4; ni++)
                Psm[wave][(lhi*4 + j) * 72 + ni*16 + l16] = f2bf(pv[ni][j]);
        __syncthreads();

        bf16x8 pf0 = *(const bf16x8*)&Psm[wave][l16 * 72 + lhi*8];
        bf16x8 pf1 = *(const bf16x8*)&Psm[wave][l16 * 72 + lhi*8 + 32];
        #pragma unroll
        for (int di = 0; di < 4; di++) {
            bf16x8 vf0 = *(const bf16x8*)&Vsm[(di*16 + l16) * 72 + lhi*8];
            bf16x8 vf1 = *(const bf16x8*)&Vsm[(di*16 + l16) * 72 + lhi*8 + 32];
            o[di] = __builtin_amdgcn_mfma_f32_16x16x32_bf16(pf0, vf0, o[di], 0, 0, 0);
            o[di] = __builtin_amdgcn_mfma_f32_16x16x32_bf16(pf1, vf1, o[di], 0, 0, 0);
        }
    }

    #pragma unroll
    for (int j = 0; j < 4; j++) {
        int qgj = qg + j;
        if (qgj >= Tn) continue;
        float inv = 1.0f / sume[j];
        #pragma unroll
        for (int di = 0; di < 4; di++)
            out[(size_t)(b*Tn + qgj) * Dn + h*64 + di*16 + l16] = f2bf(o[di][j] * inv);
    }
}

// ---------------- final fc on last position ----------------
__global__ __launch_bounds__(256) void fc_kernel(
    const float* __restrict__ x, const float* __restrict__ w,
    const float* __restrict__ bias, float* __restrict__ out)
{
    __shared__ float xs[Dn];
    int b = blockIdx.y;
    int v = blockIdx.x * 256 + threadIdx.x;
    float4 t = ((const float4*)(x + (size_t)(b*Tn + Tn - 1) * Dn))[threadIdx.x];
    ((float4*)xs)[threadIdx.x] = t;
    __syncthreads();
    float acc = bias[v];
    for (int d = 0; d < Dn; d++)
        acc = fmaf(xs[d], w[(size_t)d * Vn + v], acc);
    out[(size_t)b * Vn + v] = acc;
}

extern "C" void kernel_launch(void* const* d_in, const int* in_sizes, int n_in,
                              void* d_out, int out_size, void* d_ws, size_t ws_size,
                              hipStream_t stream)
{
    const int*   text_ids  = (const int*)d_in[0];
    const int*   prompt_ids= (const int*)d_in[1];
    const int*   output_ids= (const int*)d_in[2];
    const float* text_tab  = (const float*)d_in[3];
    const float* prompt_tab= (const float*)d_in[4];
    const float* output_tab= (const float*)d_in[5];
    const float* sep       = (const float*)d_in[6];
    const float* ln1_g     = (const float*)d_in[7];
    const float* ln1_b     = (const float*)d_in[8];
    const float* qkv_w     = (const float*)d_in[9];
    const float* out_w     = (const float*)d_in[10];
    const float* out_b     = (const float*)d_in[11];
    const float* ln2_g     = (const float*)d_in[12];
    const float* ln2_b     = (const float*)d_in[13];
    const float* ff1_w     = (const float*)d_in[14];
    const float* ff1_b     = (const float*)d_in[15];
    const float* ff2_w     = (const float*)d_in[16];
    const float* ff2_b     = (const float*)d_in[17];
    const float* fc_w      = (const float*)d_in[18];
    const float* fc_b      = (const float*)d_in[19];

    char* ws = (char*)d_ws;
    float*  x    = (float*)(ws);                    // [7184][1024] f32 = 29,425,664
    ushort* h    = (ushort*)(ws + 29425664);        // [7424][1024] bf16 = 15,204,352
    ushort* qkv  = (ushort*)(ws + 44630016);        // [7424][3072] bf16 = 45,613,056
    ushort* attn = (ushort*)(ws + 90243072);        // [7424][1024] bf16 = 15,204,352
    ushort* ff1o = (ushort*)(ws + 105447424);       // [7424][4096] bf16 = 60,817,408
    ushort* wT   = (ushort*)(ws + 166264832);       // weights bf16 [N][K]

    const size_t L_STRIDE = 12582912;        // ushorts per layer block
    const size_t OFF_QKV = 0, OFF_OUT = 3145728, OFF_FF1 = 4194304, OFF_FF2 = 8388608;
    const size_t upfront_need = 166264832ULL + 2ULL * L_STRIDE * Ln;
    const bool upfront = ws_size >= upfront_need;

    if (upfront) {
        transpose_cast_kernel<<<dim3(48,16,Ln), 256, 0, stream>>>(qkv_w, wT + OFF_QKV, Dn, 3*Dn, (size_t)Dn*3*Dn, L_STRIDE);
        transpose_cast_kernel<<<dim3(16,16,Ln), 256, 0, stream>>>(out_w, wT + OFF_OUT, Dn, Dn,   (size_t)Dn*Dn,   L_STRIDE);
        transpose_cast_kernel<<<dim3(64,16,Ln), 256, 0, stream>>>(ff1_w, wT + OFF_FF1, Dn, FFn,  (size_t)Dn*FFn,  L_STRIDE);
        transpose_cast_kernel<<<dim3(16,64,Ln), 256, 0, stream>>>(ff2_w, wT + OFF_FF2, FFn, Dn,  (size_t)FFn*Dn,  L_STRIDE);
    }

    embed_kernel<<<BT, 256, 0, stream>>>(text_ids, prompt_ids, output_ids,
                                         text_tab, prompt_tab, output_tab, sep, x);

    for (int l = 0; l < Ln; l++) {
        ushort* wb = upfront ? (wT + (size_t)l * L_STRIDE) : wT;
        if (!upfront) {
            transpose_cast_kernel<<<dim3(48,16,1), 256, 0, stream>>>(qkv_w + (size_t)l*Dn*3*Dn, wb + OFF_QKV, Dn, 3*Dn, 0, 0);
            transpose_cast_kernel<<<dim3(16,16,1), 256, 0, stream>>>(out_w + (size_t)l*Dn*Dn,   wb + OFF_OUT, Dn, Dn,   0, 0);
            transpose_cast_kernel<<<dim3(64,16,1), 256, 0, stream>>>(ff1_w + (size_t)l*Dn*FFn,  wb + OFF_FF1, Dn, FFn,  0, 0);
            transpose_cast_kernel<<<dim3(16,64,1), 256, 0, stream>>>(ff2_w + (size_t)l*FFn*Dn,  wb + OFF_FF2, FFn, Dn,  0, 0);
        }
        ln_kernel<<<BT/4, 256, 0, stream>>>(x, ln1_g + l*Dn, ln1_b + l*Dn, h);
        gemmk<128,0><<<57*24, 256, 0, stream>>>(
            h, wb + OFF_QKV, nullptr, nullptr, qkv, BT, 3*Dn, Dn, 24);
        attn_kernel<<<dim3(15, Bn, Hn), 256, 0, stream>>>(qkv, attn);
        gemmk<64,1><<<57*16, 256, 0, stream>>>(
            attn, wb + OFF_OUT, out_b + l*Dn, x, x, BT, Dn, Dn, 16);
        ln_kernel<<<BT/4, 256, 0, stream>>>(x, ln2_g + l*Dn, ln2_b + l*Dn, h);
        gemmk<128,2><<<57*32, 256, 0, stream>>>(
            h, wb + OFF_FF1, ff1_b + l*FFn, nullptr, ff1o, BT, FFn, Dn, 32);
        gemmk<64,1><<<57*16, 256, 0, stream>>>(
            ff1o, wb + OFF_FF2, ff2_b + l*Dn, x, x, BT, Dn, FFn, 16);
    }

    fc_kernel<<<dim3(Vn/256, Bn), 256, 0, stream>>>(x, fc_w, fc_b, (float*)d_out);
}

// Round 9
// 5084.970 us; speedup vs baseline: 1.2210x; 1.0116x over previous
//
#include <hip/hip_runtime.h>
#include <hip/hip_bf16.h>
#include <math.h>

#define Bn 8
#define Tn 898
#define Dn 1024
#define Hn 16
#define DHn 64
#define Ln 12
#define FFn 4096
#define Vn 1024
#define BT (Bn*Tn)   /* 7184 */

typedef short bf16x8 __attribute__((ext_vector_type(8)));
typedef float f32x4 __attribute__((ext_vector_type(4)));

__device__ __forceinline__ ushort f2bf(float f) {
    union { float f; unsigned u; } c; c.f = f;
    unsigned r = c.u + 0x7fffu + ((c.u >> 16) & 1u);
    return (ushort)(r >> 16);
}

__device__ __forceinline__ void glds16(const void* g, void* l) {
    __builtin_amdgcn_global_load_lds(
        (const __attribute__((address_space(1))) unsigned int*)g,
        (__attribute__((address_space(3))) unsigned int*)l, 16, 0, 0);
}

#define BARRIER() __builtin_amdgcn_s_barrier()
#define VMCNT0() asm volatile("s_waitcnt vmcnt(0)" ::: "memory")

// ---------------- weight transpose + cast: f32 [K][N] -> bf16 [N][K] ----------------
__global__ __launch_bounds__(256) void transpose_cast_kernel(
    const float* __restrict__ in, ushort* __restrict__ out,
    int K, int N, size_t in_ls, size_t out_ls)
{
    __shared__ ushort t[64][68];
    const float* inp = in + (size_t)blockIdx.z * in_ls;
    ushort* outp = out + (size_t)blockIdx.z * out_ls;
    int n0 = blockIdx.x * 64, k0 = blockIdx.y * 64;
    int tx = threadIdx.x & 63, ty = threadIdx.x >> 6;
    #pragma unroll
    for (int p = 0; p < 16; p++) {
        int kl = p * 4 + ty;
        t[tx][kl] = f2bf(inp[(size_t)(k0 + kl) * N + n0 + tx]);
    }
    __syncthreads();
    int tx4 = threadIdx.x & 15, ty4 = threadIdx.x >> 4;
    #pragma unroll
    for (int p = 0; p < 4; p++) {
        int nl = p * 16 + ty4;
        ushort4 v;
        v.x = t[nl][4*tx4]; v.y = t[nl][4*tx4+1]; v.z = t[nl][4*tx4+2]; v.w = t[nl][4*tx4+3];
        *(ushort4*)&outp[(size_t)(n0 + nl) * K + k0 + 4*tx4] = v;
    }
}

// ---------------- embedding + positional encoding ----------------
__global__ __launch_bounds__(256) void embed_kernel(
    const int* __restrict__ tids, const int* __restrict__ pids, const int* __restrict__ oids,
    const float* __restrict__ ttab, const float* __restrict__ ptab, const float* __restrict__ otab,
    const float* __restrict__ sep, float* __restrict__ x)
{
    int bp = blockIdx.x;
    int b = bp / Tn, pos = bp - b * Tn;
    int d0 = threadIdx.x * 4;
    float4 r;
    if (pos == 128 || pos == 385) {
        r = *(const float4*)(sep + d0);
    } else {
        int t; int id; const float* tab;
        if (pos < 128)      { t = pos;       id = tids[b*128 + t]; tab = ttab; }
        else if (pos < 385) { t = pos - 129; id = pids[b*256 + t]; tab = ptab; }
        else                { t = pos - 386; id = oids[b*512 + t]; tab = otab; }
        float4 e = *(const float4*)(tab + (size_t)id * Dn + d0);
        float pe[4];
        #pragma unroll
        for (int i = 0; i < 4; i++) {
            int d = d0 + i;
            int ii = d & 511;
            float omega = expf(-9.210340371976184f * (float)ii * (1.0f/512.0f));
            float ang = (float)t * omega;
            pe[i] = (d < 512) ? sinf(ang) : cosf(ang);
        }
        r.x = e.x + pe[0]; r.y = e.y + pe[1]; r.z = e.z + pe[2]; r.w = e.w + pe[3];
    }
    *(float4*)(x + (size_t)bp * Dn + d0) = r;
}

// ---------------- layernorm fp32 -> bf16, one row per WAVE (no LDS, no barrier) ----------
__global__ __launch_bounds__(256) void ln_kernel(
    const float* __restrict__ x, const float* __restrict__ g, const float* __restrict__ bt,
    ushort* __restrict__ out)
{
    int row = blockIdx.x * 4 + (threadIdx.x >> 6);
    int lane = threadIdx.x & 63;
    const float4* xr = (const float4*)(x + (size_t)row * Dn);
    float4 v[4];
    float s = 0.f;
    #pragma unroll
    for (int i = 0; i < 4; i++) {
        v[i] = xr[lane + 64 * i];
        s += v[i].x + v[i].y + v[i].z + v[i].w;
    }
    #pragma unroll
    for (int o = 32; o; o >>= 1) s += __shfl_xor(s, o);
    float mu = s * (1.0f / Dn);
    float s2 = 0.f;
    #pragma unroll
    for (int i = 0; i < 4; i++) {
        v[i].x -= mu; v[i].y -= mu; v[i].z -= mu; v[i].w -= mu;
        s2 += v[i].x*v[i].x + v[i].y*v[i].y + v[i].z*v[i].z + v[i].w*v[i].w;
    }
    #pragma unroll
    for (int o = 32; o; o >>= 1) s2 += __shfl_xor(s2, o);
    float rstd = rsqrtf(s2 * (1.0f / Dn) + 1e-5f);
    ushort4* orow = (ushort4*)(out + (size_t)row * Dn);
    #pragma unroll
    for (int i = 0; i < 4; i++) {
        float4 gg = ((const float4*)g)[lane + 64 * i];
        float4 bb = ((const float4*)bt)[lane + 64 * i];
        ushort4 o4;
        o4.x = f2bf(v[i].x * rstd * gg.x + bb.x);
        o4.y = f2bf(v[i].y * rstd * gg.y + bb.y);
        o4.z = f2bf(v[i].z * rstd * gg.z + bb.z);
        o4.w = f2bf(v[i].w * rstd * gg.w + bb.w);
        orow[lane + 64 * i] = o4;
    }
}

// ---------------- 2-phase double-buffered GEMM with L2-supertile rasterization -------------
// C = A(bf16 [M][K]) @ Bw(bf16 [N][K])^T. 128xBN tile, 4 waves, BK=32.
// Block order: XCD-chunked, then M-stripes of S tiles, ntt-major, mt-fast -- consecutive
// blocks share the W panel; the stripe's S A-panels (S*K*256B) stay hot in per-XCD L2.
// This attacks the measured ~8 TB/s L3-BW ceiling (R8 analysis).
// MODE 0: store bf16; MODE 1: f32 = resid + AB + bias; MODE 2: bf16 = gelu(AB + bias)
template<int BN, int MODE>
__global__ __launch_bounds__(256, 4) void gemmk(
    const ushort* __restrict__ A, const ushort* __restrict__ Bw,
    const float* __restrict__ bias, const float* __restrict__ resid,
    void* __restrict__ Cout, int M, int N, int K, int nx, int S)
{
    constexpr int NI = BN / 32;          // frags per wave in N: 4 (BN=128) or 2 (BN=64)
    __shared__ ushort sA[2][128 * 32];
    __shared__ ushort sB[2][BN * 32];

    int tid = threadIdx.x, lane = tid & 63, wv = tid >> 6;
    int wm = wv >> 1, wn = wv & 1;
    int l16 = lane & 15, lhi = lane >> 4;

    // bijective XCD-chunked swizzle
    int nb = gridDim.x, bid = blockIdx.x;
    int qq = nb >> 3, rr8 = nb & 7;
    int xcd = bid & 7, idx = bid >> 3;
    int wg = (xcd < rr8 ? xcd * (qq + 1) : rr8 * (qq + 1) + (xcd - rr8) * qq) + idx;

    // stripe rasterization: stripes of S M-tiles; within stripe ntt-major, mt-fast
    int nmt = (M + 127) >> 7;
    int fullb = nmt / S, per = S * nx;
    int mt, ntt;
    if (wg < fullb * per) {
        int band = wg / per, r2 = wg - band * per;
        ntt = r2 / S; mt = band * S + (r2 - ntt * S);
    } else {
        int r2 = wg - fullb * per, bh = nmt - fullb * S;
        ntt = r2 / bh; mt = fullb * S + (r2 - ntt * bh);
    }
    int m0 = mt * 128, n0 = ntt * BN;

    f32x4 acc[4][NI];
    #pragma unroll
    for (int i = 0; i < 4; i++)
        #pragma unroll
        for (int j = 0; j < NI; j++) acc[i][j] = (f32x4){0.f, 0.f, 0.f, 0.f};

    // staging: each glds16 covers one 16-row unit (16 rows x 64B).
    // lane -> row (lane>>2), LDS chunk (lane&3); source chunk XOR'd by (row>>1)&3 = (lane>>3)&3.
    const size_t K2 = (size_t)K * 2;
    int srow = lane >> 2;
    int schk = ((lane & 3) ^ ((lane >> 3) & 3)) * 16;
    const char* Aw0 = (const char*)A + (size_t)(m0 + wv * 16 + srow) * K2 + schk;
    const char* Aw1 = (const char*)A + (size_t)(m0 + (wv + 4) * 16 + srow) * K2 + schk;
    const char* Bp0 = (const char*)Bw + (size_t)(n0 + wv * 16 + srow) * K2 + schk;
    const char* Bp1 = (BN == 128) ? (const char*)Bw + (size_t)(n0 + (wv + 4) * 16 + srow) * K2 + schk : nullptr;

    auto stage = [&](int buf) {
        glds16(Aw0, (char*)sA[buf] + wv * 1024);
        glds16(Aw1, (char*)sA[buf] + (wv + 4) * 1024);
        glds16(Bp0, (char*)sB[buf] + wv * 1024);
        if (BN == 128)
            glds16(Bp1, (char*)sB[buf] + (wv + 4) * 1024);
        Aw0 += 64; Aw1 += 64; Bp0 += 64;
        if (BN == 128) Bp1 += 64;
    };

    // fragment reads: swizzled chunk = lhi ^ ((row>>1)&3); (row>>1)&3 == (l16>>1)&3 for all frag rows
    const int sc = (lhi ^ ((l16 >> 1) & 3)) * 8;
    auto compute = [&](int buf) {
        bf16x8 af[4], bf[NI];
        #pragma unroll
        for (int mi = 0; mi < 4; mi++)
            af[mi] = *(const bf16x8*)&sA[buf][(wm * 64 + mi * 16 + l16) * 32 + sc];
        #pragma unroll
        for (int ni = 0; ni < NI; ni++)
            bf[ni] = *(const bf16x8*)&sB[buf][(wn * (16 * NI) + ni * 16 + l16) * 32 + sc];
        #pragma unroll
        for (int mi = 0; mi < 4; mi++)
            #pragma unroll
            for (int ni = 0; ni < NI; ni++)
                acc[mi][ni] = __builtin_amdgcn_mfma_f32_16x16x32_bf16(af[mi], bf[ni], acc[mi][ni], 0, 0, 0);
    };

    int ntile = K >> 5;
    // prologue
    stage(0);
    VMCNT0();
    BARRIER();
    int cur = 0;
    for (int t = 0; t < ntile; ++t) {
        if (t + 1 < ntile) stage(cur ^ 1);   // issue next-tile loads FIRST (latency hides under MFMA)
        compute(cur);                        // ds_read + MFMA on current buffer
        VMCNT0();                            // staged writes landed
        BARRIER();                           // all waves' LDS reads done -> safe to overwrite
        cur ^= 1;
    }

    // epilogue
    #pragma unroll
    for (int mi = 0; mi < 4; mi++) {
        int rl = wm * 64 + mi * 16 + lhi * 4;
        #pragma unroll
        for (int ni = 0; ni < NI; ni++) {
            int gcol = n0 + wn * (16 * NI) + ni * 16 + l16;
            float bs = (MODE == 0) ? 0.0f : bias[gcol];
            #pragma unroll
            for (int j = 0; j < 4; j++) {
                int grow = m0 + rl + j;
                if (grow >= M) continue;
                float v = acc[mi][ni][j] + bs;
                if (MODE == 1) {
                    float rv = resid[(size_t)grow * N + gcol];
                    ((float*)Cout)[(size_t)grow * N + gcol] = rv + v;
                } else if (MODE == 2) {
                    // gelu(v) ~= v * sigmoid(1.5957691216 v + 0.0713548163 v^3)  (tanh form, |err|<~3e-4)
                    float u = v * (1.5957691216f + 0.0713548163f * v * v);
                    float g = v / (1.0f + __expf(-u));
                    ((ushort*)Cout)[(size_t)grow * N + gcol] = f2bf(g);
                } else {
                    ((ushort*)Cout)[(size_t)grow * N + gcol] = f2bf(v);
                }
            }
        }
    }
}

// ---------------- flash attention (causal), bf16 in/out ----------------
__global__ __launch_bounds__(256) void attn_kernel(
    const ushort* __restrict__ qkv, ushort* __restrict__ out)
{
    __shared__ ushort Ksm[64 * 72];
    __shared__ ushort Vsm[64 * 72];
    __shared__ ushort Psm[4][16 * 72];
    int qt = blockIdx.x, b = blockIdx.y, h = blockIdx.z;
    int tid = threadIdx.x, lane = tid & 63, wave = tid >> 6;
    int l16 = lane & 15, lhi = lane >> 4;

    int qrow = qt*64 + wave*16 + l16;
    bf16x8 qf0 = {}, qf1 = {};
    if (qrow < Tn) {
        const ushort* qp = qkv + (size_t)(b*Tn + qrow) * 3072 + h*64 + lhi*8;
        qf0 = *(const bf16x8*)qp;
        qf1 = *(const bf16x8*)(qp + 32);
    }

    f32x4 o[4];
    #pragma unroll
    for (int i = 0; i < 4; i++) o[i] = (f32x4){0.f,0.f,0.f,0.f};
    float mrun[4] = {-1e30f,-1e30f,-1e30f,-1e30f};
    float sume[4] = {0.f,0.f,0.f,0.f};

    int kr = tid >> 2, cc = (tid & 3) * 16;
    const ushort* kvbase = qkv + (size_t)(b*Tn) * 3072 + h*64 + cc;
    int qg = qt*64 + wave*16 + lhi*4;

    for (int jt = 0; jt <= qt; jt++) {
        int kvr = jt*64 + kr;
        uint4 k0 = make_uint4(0,0,0,0), k1 = k0, v0 = k0, v1 = k0;
        if (kvr < Tn) {
            const ushort* p = kvbase + (size_t)kvr * 3072;
            k0 = *(const uint4*)(p + 1024);
            k1 = *(const uint4*)(p + 1024 + 8);
            v0 = *(const uint4*)(p + 2048);
            v1 = *(const uint4*)(p + 2048 + 8);
        }
        __syncthreads();
        *(uint4*)&Ksm[kr * 72 + cc] = k0;
        *(uint4*)&Ksm[kr * 72 + cc + 8] = k1;
        {
            ushort vv[16];
            *(uint4*)&vv[0] = v0; *(uint4*)&vv[8] = v1;
            #pragma unroll
            for (int i = 0; i < 16; i++) Vsm[(cc + i) * 72 + kr] = vv[i];
        }
        __syncthreads();

        f32x4 s[4];
        #pragma unroll
        for (int ni = 0; ni < 4; ni++) {
            s[ni] = (f32x4){0.f,0.f,0.f,0.f};
            bf16x8 kf0 = *(const bf16x8*)&Ksm[(ni*16 + l16) * 72 + lhi*8];
            bf16x8 kf1 = *(const bf16x8*)&Ksm[(ni*16 + l16) * 72 + lhi*8 + 32];
            s[ni] = __builtin_amdgcn_mfma_f32_16x16x32_bf16(qf0, kf0, s[ni], 0, 0, 0);
            s[ni] = __builtin_amdgcn_mfma_f32_16x16x32_bf16(qf1, kf1, s[ni], 0, 0, 0);
        }

        float pv[4][4];
        #pragma unroll
        for (int j = 0; j < 4; j++) {
            int qgj = qg + j;
            float mx = -1e30f;
            #pragma unroll
            for (int ni = 0; ni < 4; ni++) {
                int kvg = jt*64 + ni*16 + l16;
                float e = (kvg <= qgj && kvg < Tn) ? s[ni][j] * 0.125f : -1e30f;
                pv[ni][j] = e;
                mx = fmaxf(mx, e);
            }
            #pragma unroll
            for (int m = 1; m < 16; m <<= 1) mx = fmaxf(mx, __shfl_xor(mx, m));
            float mnew = fmaxf(mrun[j], mx);
            float fac = expf(mrun[j] - mnew);
            mrun[j] = mnew;
            float rs = 0.f;
            #pragma unroll
            for (int ni = 0; ni < 4; ni++) { pv[ni][j] = expf(pv[ni][j] - mnew); rs += pv[ni][j]; }
            #pragma unroll
            for (int m = 1; m < 16; m <<= 1) rs += __shfl_xor(rs, m);
            sume[j] = sume[j] * fac + rs;
            #pragma unroll
            for (int di = 0; di < 4; di++) o[di][j] *= fac;
        }

        #pragma unroll
        for (int j = 0; j < 4; j++)
            #pragma unroll
            for (int ni = 0; ni < 4; ni++)
                Psm[wave][(lhi*4 + j) * 72 + ni*16 + l16] = f2bf(pv[ni][j]);
        __syncthreads();

        bf16x8 pf0 = *(const bf16x8*)&Psm[wave][l16 * 72 + lhi*8];
        bf16x8 pf1 = *(const bf16x8*)&Psm[wave][l16 * 72 + lhi*8 + 32];
        #pragma unroll
        for (int di = 0; di < 4; di++) {
            bf16x8 vf0 = *(const bf16x8*)&Vsm[(di*16 + l16) * 72 + lhi*8];
            bf16x8 vf1 = *(const bf16x8*)&Vsm[(di*16 + l16) * 72 + lhi*8 + 32];
            o[di] = __builtin_amdgcn_mfma_f32_16x16x32_bf16(pf0, vf0, o[di], 0, 0, 0);
            o[di] = __builtin_amdgcn_mfma_f32_16x16x32_bf16(pf1, vf1, o[di], 0, 0, 0);
        }
    }

    #pragma unroll
    for (int j = 0; j < 4; j++) {
        int qgj = qg + j;
        if (qgj >= Tn) continue;
        float inv = 1.0f / sume[j];
        #pragma unroll
        for (int di = 0; di < 4; di++)
            out[(size_t)(b*Tn + qgj) * Dn + h*64 + di*16 + l16] = f2bf(o[di][j] * inv);
    }
}

// ---------------- final fc on last position ----------------
__global__ __launch_bounds__(256) void fc_kernel(
    const float* __restrict__ x, const float* __restrict__ w,
    const float* __restrict__ bias, float* __restrict__ out)
{
    __shared__ float xs[Dn];
    int b = blockIdx.y;
    int v = blockIdx.x * 256 + threadIdx.x;
    float4 t = ((const float4*)(x + (size_t)(b*Tn + Tn - 1) * Dn))[threadIdx.x];
    ((float4*)xs)[threadIdx.x] = t;
    __syncthreads();
    float acc = bias[v];
    for (int d = 0; d < Dn; d++)
        acc = fmaf(xs[d], w[(size_t)d * Vn + v], acc);
    out[(size_t)b * Vn + v] = acc;
}

extern "C" void kernel_launch(void* const* d_in, const int* in_sizes, int n_in,
                              void* d_out, int out_size, void* d_ws, size_t ws_size,
                              hipStream_t stream)
{
    const int*   text_ids  = (const int*)d_in[0];
    const int*   prompt_ids= (const int*)d_in[1];
    const int*   output_ids= (const int*)d_in[2];
    const float* text_tab  = (const float*)d_in[3];
    const float* prompt_tab= (const float*)d_in[4];
    const float* output_tab= (const float*)d_in[5];
    const float* sep       = (const float*)d_in[6];
    const float* ln1_g     = (const float*)d_in[7];
    const float* ln1_b     = (const float*)d_in[8];
    const float* qkv_w     = (const float*)d_in[9];
    const float* out_w     = (const float*)d_in[10];
    const float* out_b     = (const float*)d_in[11];
    const float* ln2_g     = (const float*)d_in[12];
    const float* ln2_b     = (const float*)d_in[13];
    const float* ff1_w     = (const float*)d_in[14];
    const float* ff1_b     = (const float*)d_in[15];
    const float* ff2_w     = (const float*)d_in[16];
    const float* ff2_b     = (const float*)d_in[17];
    const float* fc_w      = (const float*)d_in[18];
    const float* fc_b      = (const float*)d_in[19];

    char* ws = (char*)d_ws;
    float*  x    = (float*)(ws);                    // [7184][1024] f32 = 29,425,664
    ushort* h    = (ushort*)(ws + 29425664);        // [7424][1024] bf16 = 15,204,352
    ushort* qkv  = (ushort*)(ws + 44630016);        // [7424][3072] bf16 = 45,613,056
    ushort* attn = (ushort*)(ws + 90243072);        // [7424][1024] bf16 = 15,204,352
    ushort* ff1o = (ushort*)(ws + 105447424);       // [7424][4096] bf16 = 60,817,408
    ushort* wT   = (ushort*)(ws + 166264832);       // weights bf16 [N][K]

    const size_t L_STRIDE = 12582912;        // ushorts per layer block
    const size_t OFF_QKV = 0, OFF_OUT = 3145728, OFF_FF1 = 4194304, OFF_FF2 = 8388608;
    const size_t upfront_need = 166264832ULL + 2ULL * L_STRIDE * Ln;
    const bool upfront = ws_size >= upfront_need;

    if (upfront) {
        transpose_cast_kernel<<<dim3(48,16,Ln), 256, 0, stream>>>(qkv_w, wT + OFF_QKV, Dn, 3*Dn, (size_t)Dn*3*Dn, L_STRIDE);
        transpose_cast_kernel<<<dim3(16,16,Ln), 256, 0, stream>>>(out_w, wT + OFF_OUT, Dn, Dn,   (size_t)Dn*Dn,   L_STRIDE);
        transpose_cast_kernel<<<dim3(64,16,Ln), 256, 0, stream>>>(ff1_w, wT + OFF_FF1, Dn, FFn,  (size_t)Dn*FFn,  L_STRIDE);
        transpose_cast_kernel<<<dim3(16,64,Ln), 256, 0, stream>>>(ff2_w, wT + OFF_FF2, FFn, Dn,  (size_t)FFn*Dn,  L_STRIDE);
    }

    embed_kernel<<<BT, 256, 0, stream>>>(text_ids, prompt_ids, output_ids,
                                         text_tab, prompt_tab, output_tab, sep, x);

    for (int l = 0; l < Ln; l++) {
        ushort* wb = upfront ? (wT + (size_t)l * L_STRIDE) : wT;
        if (!upfront) {
            transpose_cast_kernel<<<dim3(48,16,1), 256, 0, stream>>>(qkv_w + (size_t)l*Dn*3*Dn, wb + OFF_QKV, Dn, 3*Dn, 0, 0);
            transpose_cast_kernel<<<dim3(16,16,1), 256, 0, stream>>>(out_w + (size_t)l*Dn*Dn,   wb + OFF_OUT, Dn, Dn,   0, 0);
            transpose_cast_kernel<<<dim3(64,16,1), 256, 0, stream>>>(ff1_w + (size_t)l*Dn*FFn,  wb + OFF_FF1, Dn, FFn,  0, 0);
            transpose_cast_kernel<<<dim3(16,64,1), 256, 0, stream>>>(ff2_w + (size_t)l*FFn*Dn,  wb + OFF_FF2, FFn, Dn,  0, 0);
        }
        ln_kernel<<<BT/4, 256, 0, stream>>>(x, ln1_g + l*Dn, ln1_b + l*Dn, h);
        gemmk<128,0><<<57*24, 256, 0, stream>>>(
            h, wb + OFF_QKV, nullptr, nullptr, qkv, BT, 3*Dn, Dn, 24, 8);
        attn_kernel<<<dim3(15, Bn, Hn), 256, 0, stream>>>(qkv, attn);
        gemmk<64,1><<<57*16, 256, 0, stream>>>(
            attn, wb + OFF_OUT, out_b + l*Dn, x, x, BT, Dn, Dn, 16, 8);
        ln_kernel<<<BT/4, 256, 0, stream>>>(x, ln2_g + l*Dn, ln2_b + l*Dn, h);
        gemmk<128,2><<<57*32, 256, 0, stream>>>(
            h, wb + OFF_FF1, ff1_b + l*FFn, nullptr, ff1o, BT, FFn, Dn, 32, 8);
        gemmk<64,1><<<57*16, 256, 0, stream>>>(
            ff1o, wb + OFF_FF2, ff2_b + l*Dn, x, x, BT, Dn, FFn, 16, 3);
    }

    fc_kernel<<<dim3(Vn/256, Bn), 256, 0, stream>>>(x, fc_w, fc_b, (float*)d_out);
}

// Round 10
// 4932.683 us; speedup vs baseline: 1.2587x; 1.0309x over previous
//
#include <hip/hip_runtime.h>
#include <hip/hip_bf16.h>
#include <math.h>

#define Bn 8
#define Tn 898
#define Dn 1024
#define Hn 16
#define DHn 64
#define Ln 12
#define FFn 4096
#define Vn 1024
#define BT (Bn*Tn)   /* 7184 */

typedef short bf16x8 __attribute__((ext_vector_type(8)));
typedef float f32x4 __attribute__((ext_vector_type(4)));

__device__ __forceinline__ ushort f2bf(float f) {
    union { float f; unsigned u; } c; c.f = f;
    unsigned r = c.u + 0x7fffu + ((c.u >> 16) & 1u);
    return (ushort)(r >> 16);
}

__device__ __forceinline__ void glds16(const void* g, void* l) {
    __builtin_amdgcn_global_load_lds(
        (const __attribute__((address_space(1))) unsigned int*)g,
        (__attribute__((address_space(3))) unsigned int*)l, 16, 0, 0);
}

#define BARRIER() __builtin_amdgcn_s_barrier()
#define VMCNT0() asm volatile("s_waitcnt vmcnt(0)" ::: "memory")

// ---------------- weight transpose + cast: f32 [K][N] -> bf16 [N][K] ----------------
__global__ __launch_bounds__(256) void transpose_cast_kernel(
    const float* __restrict__ in, ushort* __restrict__ out,
    int K, int N, size_t in_ls, size_t out_ls)
{
    __shared__ ushort t[64][68];
    const float* inp = in + (size_t)blockIdx.z * in_ls;
    ushort* outp = out + (size_t)blockIdx.z * out_ls;
    int n0 = blockIdx.x * 64, k0 = blockIdx.y * 64;
    int tx = threadIdx.x & 63, ty = threadIdx.x >> 6;
    #pragma unroll
    for (int p = 0; p < 16; p++) {
        int kl = p * 4 + ty;
        t[tx][kl] = f2bf(inp[(size_t)(k0 + kl) * N + n0 + tx]);
    }
    __syncthreads();
    int tx4 = threadIdx.x & 15, ty4 = threadIdx.x >> 4;
    #pragma unroll
    for (int p = 0; p < 4; p++) {
        int nl = p * 16 + ty4;
        ushort4 v;
        v.x = t[nl][4*tx4]; v.y = t[nl][4*tx4+1]; v.z = t[nl][4*tx4+2]; v.w = t[nl][4*tx4+3];
        *(ushort4*)&outp[(size_t)(n0 + nl) * K + k0 + 4*tx4] = v;
    }
}

// ---------------- embedding + positional encoding ----------------
__global__ __launch_bounds__(256) void embed_kernel(
    const int* __restrict__ tids, const int* __restrict__ pids, const int* __restrict__ oids,
    const float* __restrict__ ttab, const float* __restrict__ ptab, const float* __restrict__ otab,
    const float* __restrict__ sep, float* __restrict__ x)
{
    int bp = blockIdx.x;
    int b = bp / Tn, pos = bp - b * Tn;
    int d0 = threadIdx.x * 4;
    float4 r;
    if (pos == 128 || pos == 385) {
        r = *(const float4*)(sep + d0);
    } else {
        int t; int id; const float* tab;
        if (pos < 128)      { t = pos;       id = tids[b*128 + t]; tab = ttab; }
        else if (pos < 385) { t = pos - 129; id = pids[b*256 + t]; tab = ptab; }
        else                { t = pos - 386; id = oids[b*512 + t]; tab = otab; }
        float4 e = *(const float4*)(tab + (size_t)id * Dn + d0);
        float pe[4];
        #pragma unroll
        for (int i = 0; i < 4; i++) {
            int d = d0 + i;
            int ii = d & 511;
            float omega = expf(-9.210340371976184f * (float)ii * (1.0f/512.0f));
            float ang = (float)t * omega;
            pe[i] = (d < 512) ? sinf(ang) : cosf(ang);
        }
        r.x = e.x + pe[0]; r.y = e.y + pe[1]; r.z = e.z + pe[2]; r.w = e.w + pe[3];
    }
    *(float4*)(x + (size_t)bp * Dn + d0) = r;
}

// ---------------- layernorm fp32 -> bf16, one row per WAVE (no LDS, no barrier) ----------
__global__ __launch_bounds__(256) void ln_kernel(
    const float* __restrict__ x, const float* __restrict__ g, const float* __restrict__ bt,
    ushort* __restrict__ out)
{
    int row = blockIdx.x * 4 + (threadIdx.x >> 6);
    int lane = threadIdx.x & 63;
    const float4* xr = (const float4*)(x + (size_t)row * Dn);
    float4 v[4];
    float s = 0.f;
    #pragma unroll
    for (int i = 0; i < 4; i++) {
        v[i] = xr[lane + 64 * i];
        s += v[i].x + v[i].y + v[i].z + v[i].w;
    }
    #pragma unroll
    for (int o = 32; o; o >>= 1) s += __shfl_xor(s, o);
    float mu = s * (1.0f / Dn);
    float s2 = 0.f;
    #pragma unroll
    for (int i = 0; i < 4; i++) {
        v[i].x -= mu; v[i].y -= mu; v[i].z -= mu; v[i].w -= mu;
        s2 += v[i].x*v[i].x + v[i].y*v[i].y + v[i].z*v[i].z + v[i].w*v[i].w;
    }
    #pragma unroll
    for (int o = 32; o; o >>= 1) s2 += __shfl_xor(s2, o);
    float rstd = rsqrtf(s2 * (1.0f / Dn) + 1e-5f);
    ushort4* orow = (ushort4*)(out + (size_t)row * Dn);
    #pragma unroll
    for (int i = 0; i < 4; i++) {
        float4 gg = ((const float4*)g)[lane + 64 * i];
        float4 bb = ((const float4*)bt)[lane + 64 * i];
        ushort4 o4;
        o4.x = f2bf(v[i].x * rstd * gg.x + bb.x);
        o4.y = f2bf(v[i].y * rstd * gg.y + bb.y);
        o4.z = f2bf(v[i].z * rstd * gg.z + bb.z);
        o4.w = f2bf(v[i].w * rstd * gg.w + bb.w);
        orow[lane + 64 * i] = o4;
    }
}

// ---------------- 2-phase double-buffered GEMM, BMxBN, L2-supertile rasterization ----------
// C = A(bf16 [M][K]) @ Bw(bf16 [N][K])^T. 4 waves (2x2), per-wave (BM/2)x(BN/2), BK=32.
// BM=64/BN=128 for N=1024 GEMMs: halves A-panel L3 re-reads vs BN=64 (R9 analysis: ff2 is
// A-panel-L3-BW bound) and raises MFMA:ds_read ratio to 2.67.
// MODE 0: store bf16; MODE 1: f32 = resid + AB + bias; MODE 2: bf16 = gelu(AB + bias)
template<int BM, int BN, int MODE>
__global__ __launch_bounds__(256, 4) void gemmk(
    const ushort* __restrict__ A, const ushort* __restrict__ Bw,
    const float* __restrict__ bias, const float* __restrict__ resid,
    void* __restrict__ Cout, int M, int N, int K, int nx, int S)
{
    constexpr int MI = BM / 32, NI = BN / 32;     // frags per wave
    constexpr int UA = BM / 64, UB = BN / 64;     // 16-row staging units per wave
    __shared__ ushort sA[2][BM * 32];
    __shared__ ushort sB[2][BN * 32];

    int tid = threadIdx.x, lane = tid & 63, wv = tid >> 6;
    int wm = wv >> 1, wn = wv & 1;
    int l16 = lane & 15, lhi = lane >> 4;

    // bijective XCD-chunked swizzle
    int nb = gridDim.x, bid = blockIdx.x;
    int qq = nb >> 3, rr8 = nb & 7;
    int xcd = bid & 7, idx = bid >> 3;
    int wg = (xcd < rr8 ? xcd * (qq + 1) : rr8 * (qq + 1) + (xcd - rr8) * qq) + idx;

    // stripe rasterization: stripes of S M-tiles; within stripe ntt-major, mt-fast
    int nmt = (M + BM - 1) / BM;
    int fullb = nmt / S, per = S * nx;
    int mt, ntt;
    if (wg < fullb * per) {
        int band = wg / per, r2 = wg - band * per;
        ntt = r2 / S; mt = band * S + (r2 - ntt * S);
    } else {
        int r2 = wg - fullb * per, bh = nmt - fullb * S;
        ntt = r2 / bh; mt = fullb * S + (r2 - ntt * bh);
    }
    int m0 = mt * BM, n0 = ntt * BN;

    f32x4 acc[MI][NI];
    #pragma unroll
    for (int i = 0; i < MI; i++)
        #pragma unroll
        for (int j = 0; j < NI; j++) acc[i][j] = (f32x4){0.f, 0.f, 0.f, 0.f};

    // staging: each glds16 covers one 16-row unit (16 rows x 64B).
    // lane -> row (lane>>2), LDS chunk (lane&3); source chunk XOR'd by (row>>1)&3 = (lane>>3)&3.
    const size_t K2 = (size_t)K * 2;
    int srow = lane >> 2;
    int schk = ((lane & 3) ^ ((lane >> 3) & 3)) * 16;
    const char* Ap[UA];
    const char* Bp[UB];
    #pragma unroll
    for (int i = 0; i < UA; i++)
        Ap[i] = (const char*)A + (size_t)(m0 + (wv + 4 * i) * 16 + srow) * K2 + schk;
    #pragma unroll
    for (int i = 0; i < UB; i++)
        Bp[i] = (const char*)Bw + (size_t)(n0 + (wv + 4 * i) * 16 + srow) * K2 + schk;

    auto stage = [&](int buf) {
        #pragma unroll
        for (int i = 0; i < UA; i++) {
            glds16(Ap[i], (char*)sA[buf] + (wv + 4 * i) * 1024);
            Ap[i] += 64;
        }
        #pragma unroll
        for (int i = 0; i < UB; i++) {
            glds16(Bp[i], (char*)sB[buf] + (wv + 4 * i) * 1024);
            Bp[i] += 64;
        }
    };

    // fragment reads: swizzled chunk = lhi ^ ((row>>1)&3); (row>>1)&3 == (l16>>1)&3 for all frag rows
    const int sc = (lhi ^ ((l16 >> 1) & 3)) * 8;
    auto compute = [&](int buf) {
        bf16x8 af[MI], bf[NI];
        #pragma unroll
        for (int mi = 0; mi < MI; mi++)
            af[mi] = *(const bf16x8*)&sA[buf][(wm * (16 * MI) + mi * 16 + l16) * 32 + sc];
        #pragma unroll
        for (int ni = 0; ni < NI; ni++)
            bf[ni] = *(const bf16x8*)&sB[buf][(wn * (16 * NI) + ni * 16 + l16) * 32 + sc];
        #pragma unroll
        for (int mi = 0; mi < MI; mi++)
            #pragma unroll
            for (int ni = 0; ni < NI; ni++)
                acc[mi][ni] = __builtin_amdgcn_mfma_f32_16x16x32_bf16(af[mi], bf[ni], acc[mi][ni], 0, 0, 0);
    };

    int ntile = K >> 5;
    // prologue
    stage(0);
    VMCNT0();
    BARRIER();
    int cur = 0;
    for (int t = 0; t < ntile; ++t) {
        if (t + 1 < ntile) stage(cur ^ 1);   // issue next-tile loads FIRST (latency hides under MFMA)
        compute(cur);                        // ds_read + MFMA on current buffer
        VMCNT0();                            // staged writes landed
        BARRIER();                           // all waves' LDS reads done -> safe to overwrite
        cur ^= 1;
    }

    // epilogue
    #pragma unroll
    for (int mi = 0; mi < MI; mi++) {
        int rl = wm * (16 * MI) + mi * 16 + lhi * 4;
        #pragma unroll
        for (int ni = 0; ni < NI; ni++) {
            int gcol = n0 + wn * (16 * NI) + ni * 16 + l16;
            float bs = (MODE == 0) ? 0.0f : bias[gcol];
            #pragma unroll
            for (int j = 0; j < 4; j++) {
                int grow = m0 + rl + j;
                if (grow >= M) continue;
                float v = acc[mi][ni][j] + bs;
                if (MODE == 1) {
                    float rv = resid[(size_t)grow * N + gcol];
                    ((float*)Cout)[(size_t)grow * N + gcol] = rv + v;
                } else if (MODE == 2) {
                    // gelu(v) ~= v * sigmoid(1.5957691216 v + 0.0713548163 v^3)  (tanh form, |err|<~3e-4)
                    float u = v * (1.5957691216f + 0.0713548163f * v * v);
                    float g = v / (1.0f + __expf(-u));
                    ((ushort*)Cout)[(size_t)grow * N + gcol] = f2bf(g);
                } else {
                    ((ushort*)Cout)[(size_t)grow * N + gcol] = f2bf(v);
                }
            }
        }
    }
}

// ---------------- flash attention (causal), bf16 in/out ----------------
__global__ __launch_bounds__(256) void attn_kernel(
    const ushort* __restrict__ qkv, ushort* __restrict__ out)
{
    __shared__ ushort Ksm[64 * 72];
    __shared__ ushort Vsm[64 * 72];
    __shared__ ushort Psm[4][16 * 72];
    int qt = blockIdx.x, b = blockIdx.y, h = blockIdx.z;
    int tid = threadIdx.x, lane = tid & 63, wave = tid >> 6;
    int l16 = lane & 15, lhi = lane >> 4;

    int qrow = qt*64 + wave*16 + l16;
    bf16x8 qf0 = {}, qf1 = {};
    if (qrow < Tn) {
        const ushort* qp = qkv + (size_t)(b*Tn + qrow) * 3072 + h*64 + lhi*8;
        qf0 = *(const bf16x8*)qp;
        qf1 = *(const bf16x8*)(qp + 32);
    }

    f32x4 o[4];
    #pragma unroll
    for (int i = 0; i < 4; i++) o[i] = (f32x4){0.f,0.f,0.f,0.f};
    float mrun[4] = {-1e30f,-1e30f,-1e30f,-1e30f};
    float sume[4] = {0.f,0.f,0.f,0.f};

    int kr = tid >> 2, cc = (tid & 3) * 16;
    const ushort* kvbase = qkv + (size_t)(b*Tn) * 3072 + h*64 + cc;
    int qg = qt*64 + wave*16 + lhi*4;

    for (int jt = 0; jt <= qt; jt++) {
        int kvr = jt*64 + kr;
        uint4 k0 = make_uint4(0,0,0,0), k1 = k0, v0 = k0, v1 = k0;
        if (kvr < Tn) {
            const ushort* p = kvbase + (size_t)kvr * 3072;
            k0 = *(const uint4*)(p + 1024);
            k1 = *(const uint4*)(p + 1024 + 8);
            v0 = *(const uint4*)(p + 2048);
            v1 = *(const uint4*)(p + 2048 + 8);
        }
        __syncthreads();
        *(uint4*)&Ksm[kr * 72 + cc] = k0;
        *(uint4*)&Ksm[kr * 72 + cc + 8] = k1;
        {
            ushort vv[16];
            *(uint4*)&vv[0] = v0; *(uint4*)&vv[8] = v1;
            #pragma unroll
            for (int i = 0; i < 16; i++) Vsm[(cc + i) * 72 + kr] = vv[i];
        }
        __syncthreads();

        f32x4 s[4];
        #pragma unroll
        for (int ni = 0; ni < 4; ni++) {
            s[ni] = (f32x4){0.f,0.f,0.f,0.f};
            bf16x8 kf0 = *(const bf16x8*)&Ksm[(ni*16 + l16) * 72 + lhi*8];
            bf16x8 kf1 = *(const bf16x8*)&Ksm[(ni*16 + l16) * 72 + lhi*8 + 32];
            s[ni] = __builtin_amdgcn_mfma_f32_16x16x32_bf16(qf0, kf0, s[ni], 0, 0, 0);
            s[ni] = __builtin_amdgcn_mfma_f32_16x16x32_bf16(qf1, kf1, s[ni], 0, 0, 0);
        }

        float pv[4][4];
        #pragma unroll
        for (int j = 0; j < 4; j++) {
            int qgj = qg + j;
            float mx = -1e30f;
            #pragma unroll
            for (int ni = 0; ni < 4; ni++) {
                int kvg = jt*64 + ni*16 + l16;
                float e = (kvg <= qgj && kvg < Tn) ? s[ni][j] * 0.125f : -1e30f;
                pv[ni][j] = e;
                mx = fmaxf(mx, e);
            }
            #pragma unroll
            for (int m = 1; m < 16; m <<= 1) mx = fmaxf(mx, __shfl_xor(mx, m));
            float mnew = fmaxf(mrun[j], mx);
            float fac = expf(mrun[j] - mnew);
            mrun[j] = mnew;
            float rs = 0.f;
            #pragma unroll
            for (int ni = 0; ni < 4; ni++) { pv[ni][j] = expf(pv[ni][j] - mnew); rs += pv[ni][j]; }
            #pragma unroll
            for (int m = 1; m < 16; m <<= 1) rs += __shfl_xor(rs, m);
            sume[j] = sume[j] * fac + rs;
            #pragma unroll
            for (int di = 0; di < 4; di++) o[di][j] *= fac;
        }

        #pragma unroll
        for (int j = 0; j < 4; j++)
            #pragma unroll
            for (int ni = 0; ni < 4; ni++)
                Psm[wave][(lhi*4 + j) * 72 + ni*16 + l16] = f2bf(pv[ni][j]);
        __syncthreads();

        bf16x8 pf0 = *(const bf16x8*)&Psm[wave][l16 * 72 + lhi*8];
        bf16x8 pf1 = *(const bf16x8*)&Psm[wave][l16 * 72 + lhi*8 + 32];
        #pragma unroll
        for (int di = 0; di < 4; di++) {
            bf16x8 vf0 = *(const bf16x8*)&Vsm[(di*16 + l16) * 72 + lhi*8];
            bf16x8 vf1 = *(const bf16x8*)&Vsm[(di*16 + l16) * 72 + lhi*8 + 32];
            o[di] = __builtin_amdgcn_mfma_f32_16x16x32_bf16(pf0, vf0, o[di], 0, 0, 0);
            o[di] = __builtin_amdgcn_mfma_f32_16x16x32_bf16(pf1, vf1, o[di], 0, 0, 0);
        }
    }

    #pragma unroll
    for (int j = 0; j < 4; j++) {
        int qgj = qg + j;
        if (qgj >= Tn) continue;
        float inv = 1.0f / sume[j];
        #pragma unroll
        for (int di = 0; di < 4; di++)
            out[(size_t)(b*Tn + qgj) * Dn + h*64 + di*16 + l16] = f2bf(o[di][j] * inv);
    }
}

// ---------------- final fc on last position ----------------
__global__ __launch_bounds__(256) void fc_kernel(
    const float* __restrict__ x, const float* __restrict__ w,
    const float* __restrict__ bias, float* __restrict__ out)
{
    __shared__ float xs[Dn];
    int b = blockIdx.y;
    int v = blockIdx.x * 256 + threadIdx.x;
    float4 t = ((const float4*)(x + (size_t)(b*Tn + Tn - 1) * Dn))[threadIdx.x];
    ((float4*)xs)[threadIdx.x] = t;
    __syncthreads();
    float acc = bias[v];
    for (int d = 0; d < Dn; d++)
        acc = fmaf(xs[d], w[(size_t)d * Vn + v], acc);
    out[(size_t)b * Vn + v] = acc;
}

extern "C" void kernel_launch(void* const* d_in, const int* in_sizes, int n_in,
                              void* d_out, int out_size, void* d_ws, size_t ws_size,
                              hipStream_t stream)
{
    const int*   text_ids  = (const int*)d_in[0];
    const int*   prompt_ids= (const int*)d_in[1];
    const int*   output_ids= (const int*)d_in[2];
    const float* text_tab  = (const float*)d_in[3];
    const float* prompt_tab= (const float*)d_in[4];
    const float* output_tab= (const float*)d_in[5];
    const float* sep       = (const float*)d_in[6];
    const float* ln1_g     = (const float*)d_in[7];
    const float* ln1_b     = (const float*)d_in[8];
    const float* qkv_w     = (const float*)d_in[9];
    const float* out_w     = (const float*)d_in[10];
    const float* out_b     = (const float*)d_in[11];
    const float* ln2_g     = (const float*)d_in[12];
    const float* ln2_b     = (const float*)d_in[13];
    const float* ff1_w     = (const float*)d_in[14];
    const float* ff1_b     = (const float*)d_in[15];
    const float* ff2_w     = (const float*)d_in[16];
    const float* ff2_b     = (const float*)d_in[17];
    const float* fc_w      = (const float*)d_in[18];
    const float* fc_b      = (const float*)d_in[19];

    char* ws = (char*)d_ws;
    float*  x    = (float*)(ws);                    // [7184][1024] f32 = 29,425,664
    ushort* h    = (ushort*)(ws + 29425664);        // [7424][1024] bf16 = 15,204,352
    ushort* qkv  = (ushort*)(ws + 44630016);        // [7424][3072] bf16 = 45,613,056
    ushort* attn = (ushort*)(ws + 90243072);        // [7424][1024] bf16 = 15,204,352
    ushort* ff1o = (ushort*)(ws + 105447424);       // [7424][4096] bf16 = 60,817,408
    ushort* wT   = (ushort*)(ws + 166264832);       // weights bf16 [N][K]

    const size_t L_STRIDE = 12582912;        // ushorts per layer block
    const size_t OFF_QKV = 0, OFF_OUT = 3145728, OFF_FF1 = 4194304, OFF_FF2 = 8388608;
    const size_t upfront_need = 166264832ULL + 2ULL * L_STRIDE * Ln;
    const bool upfront = ws_size >= upfront_need;

    if (upfront) {
        transpose_cast_kernel<<<dim3(48,16,Ln), 256, 0, stream>>>(qkv_w, wT + OFF_QKV, Dn, 3*Dn, (size_t)Dn*3*Dn, L_STRIDE);
        transpose_cast_kernel<<<dim3(16,16,Ln), 256, 0, stream>>>(out_w, wT + OFF_OUT, Dn, Dn,   (size_t)Dn*Dn,   L_STRIDE);
        transpose_cast_kernel<<<dim3(64,16,Ln), 256, 0, stream>>>(ff1_w, wT + OFF_FF1, Dn, FFn,  (size_t)Dn*FFn,  L_STRIDE);
        transpose_cast_kernel<<<dim3(16,64,Ln), 256, 0, stream>>>(ff2_w, wT + OFF_FF2, FFn, Dn,  (size_t)FFn*Dn,  L_STRIDE);
    }

    embed_kernel<<<BT, 256, 0, stream>>>(text_ids, prompt_ids, output_ids,
                                         text_tab, prompt_tab, output_tab, sep, x);

    for (int l = 0; l < Ln; l++) {
        ushort* wb = upfront ? (wT + (size_t)l * L_STRIDE) : wT;
        if (!upfront) {
            transpose_cast_kernel<<<dim3(48,16,1), 256, 0, stream>>>(qkv_w + (size_t)l*Dn*3*Dn, wb + OFF_QKV, Dn, 3*Dn, 0, 0);
            transpose_cast_kernel<<<dim3(16,16,1), 256, 0, stream>>>(out_w + (size_t)l*Dn*Dn,   wb + OFF_OUT, Dn, Dn,   0, 0);
            transpose_cast_kernel<<<dim3(64,16,1), 256, 0, stream>>>(ff1_w + (size_t)l*Dn*FFn,  wb + OFF_FF1, Dn, FFn,  0, 0);
            transpose_cast_kernel<<<dim3(16,64,1), 256, 0, stream>>>(ff2_w + (size_t)l*FFn*Dn,  wb + OFF_FF2, FFn, Dn,  0, 0);
        }
        ln_kernel<<<BT/4, 256, 0, stream>>>(x, ln1_g + l*Dn, ln1_b + l*Dn, h);
        gemmk<128,128,0><<<57*24, 256, 0, stream>>>(
            h, wb + OFF_QKV, nullptr, nullptr, qkv, BT, 3*Dn, Dn, 24, 8);
        attn_kernel<<<dim3(15, Bn, Hn), 256, 0, stream>>>(qkv, attn);
        gemmk<64,128,1><<<113*8, 256, 0, stream>>>(
            attn, wb + OFF_OUT, out_b + l*Dn, x, x, BT, Dn, Dn, 8, 4);
        ln_kernel<<<BT/4, 256, 0, stream>>>(x, ln2_g + l*Dn, ln2_b + l*Dn, h);
        gemmk<128,128,2><<<57*32, 256, 0, stream>>>(
            h, wb + OFF_FF1, ff1_b + l*FFn, nullptr, ff1o, BT, FFn, Dn, 32, 8);
        gemmk<64,128,1><<<113*8, 256, 0, stream>>>(
            ff1o, wb + OFF_FF2, ff2_b + l*Dn, x, x, BT, Dn, FFn, 8, 4);
    }

    fc_kernel<<<dim3(Vn/256, Bn), 256, 0, stream>>>(x, fc_w, fc_b, (float*)d_out);
}